// Round 9
// baseline (496.466 us; speedup 1.0000x reference)
//
#include <hip/hip_runtime.h>
#include <hip/hip_bf16.h>
#include <stdint.h>

// Problem constants (B=1). I/O dtype: fp32. Internals bf16 (MFMA path).
#define S_LEN 2048
#define HID   2048
#define NQH   32
#define NKVH  8
#define HD    64
#define QKV_O 3072      // (32 + 2*8) * 64
#define K_COL 2048      // col offset of K block in qkv row
#define V_COL 2560      // col offset of V block in qkv row

typedef unsigned short ushort_t;
typedef __bf16 bf16x8 __attribute__((ext_vector_type(8)));
typedef float  f32x4  __attribute__((ext_vector_type(4)));

#define GLB(p) ((const __attribute__((address_space(1))) void*)(p))
#define LDSP(p) ((__attribute__((address_space(3))) void*)(p))

__device__ __forceinline__ ushort_t f2bf(float f) {
    unsigned int x = __float_as_uint(f);
    unsigned int r = (x + 0x7fffu + ((x >> 16) & 1u)) >> 16;   // RNE
    return (ushort_t)r;
}
__device__ __forceinline__ unsigned int pk_bf16(float a, float b) {
    __hip_bfloat162 h = __float22bfloat162_rn(make_float2(a, b));
    unsigned int r;
    __builtin_memcpy(&r, &h, 4);
    return r;
}
__device__ __forceinline__ void unpack8(float* dst, uint4 u) {
    dst[0] = __uint_as_float(u.x << 16); dst[1] = __uint_as_float(u.x & 0xffff0000u);
    dst[2] = __uint_as_float(u.y << 16); dst[3] = __uint_as_float(u.y & 0xffff0000u);
    dst[4] = __uint_as_float(u.z << 16); dst[5] = __uint_as_float(u.z & 0xffff0000u);
    dst[6] = __uint_as_float(u.w << 16); dst[7] = __uint_as_float(u.w & 0xffff0000u);
}

// ---------------------------------------------------------------------------
// convert3: fp32 -> bf16 for x, w_qkv, w_out (unchanged)
// ---------------------------------------------------------------------------
#define XN8 (S_LEN * HID / 8)          // 524288
#define QN8 (QKV_O * HID / 8)          // 786432
#define ON8 (HID * HID / 8)            // 524288

__global__ __launch_bounds__(256) void convert3(
    const float* __restrict__ x, const float* __restrict__ wq,
    const float* __restrict__ wo, ushort_t* __restrict__ xb,
    ushort_t* __restrict__ wqb, ushort_t* __restrict__ wob) {
    int i = blockIdx.x * 256 + threadIdx.x;
    const float* s; ushort_t* d; int off;
    if (i < XN8)            { s = x;  d = xb;  off = i; }
    else if (i < XN8 + QN8) { s = wq; d = wqb; off = i - XN8; }
    else                    { s = wo; d = wob; off = i - XN8 - QN8; }
    const float4* sp = (const float4*)s + (size_t)off * 2;
    float4 a = sp[0], b = sp[1];
    *(uint4*)(d + (size_t)off * 8) = make_uint4(
        pk_bf16(a.x, a.y), pk_bf16(a.z, a.w),
        pk_bf16(b.x, b.y), pk_bf16(b.z, b.w));
}

// ---------------------------------------------------------------------------
// gemm64: pure-bf16 GEMM, 64x128 (MxN) tile, BK=32 (unchanged from round 8)
// ---------------------------------------------------------------------------
template<bool CF32>
__global__ __launch_bounds__(256) void gemm64(
    const ushort_t* __restrict__ A, const ushort_t* __restrict__ Bt,
    void* __restrict__ Cp, int M, int N, int K) {
    __shared__ ushort_t As[64][32];
    __shared__ ushort_t Bs[128][32];

    const int t    = threadIdx.x;
    const int wave = t >> 6;
    const int lane = t & 63;
    const int quad = lane >> 4;
    const int l16  = lane & 15;
    const int wm   = (wave >> 1) << 5;
    const int wn   = (wave & 1)  << 6;
    const int bm   = blockIdx.y * 64;
    const int bn   = blockIdx.x * 128;
    const int lrow = lane >> 2;
    const int lcol = (lane & 3) << 3;

    f32x4 acc[2][4];
    #pragma unroll
    for (int i = 0; i < 2; i++)
        #pragma unroll
        for (int j = 0; j < 4; j++) {
            f32x4 z = {0.f, 0.f, 0.f, 0.f};
            acc[i][j] = z;
        }

    const ushort_t* a0 = &A[(size_t)(bm + wave * 16 + lrow) * K + lcol];
    const ushort_t* b0 = &Bt[(size_t)(bn + wave * 32 + lrow) * K + lcol];
    const size_t r16 = (size_t)16 * K;

    for (int k0 = 0; k0 < K; k0 += 32) {
        __syncthreads();
        __builtin_amdgcn_global_load_lds(GLB(a0 + k0),       LDSP(&As[wave * 16][0]),      16, 0, 0);
        __builtin_amdgcn_global_load_lds(GLB(b0 + k0),       LDSP(&Bs[wave * 32][0]),      16, 0, 0);
        __builtin_amdgcn_global_load_lds(GLB(b0 + k0 + r16), LDSP(&Bs[wave * 32 + 16][0]), 16, 0, 0);
        __syncthreads();

        bf16x8 af[2], bfr[4];
        #pragma unroll
        for (int i = 0; i < 2; i++)
            af[i] = *(const bf16x8*)&As[wm + i * 16 + l16][quad * 8];
        #pragma unroll
        for (int j = 0; j < 4; j++)
            bfr[j] = *(const bf16x8*)&Bs[wn + j * 16 + l16][quad * 8];

        #pragma unroll
        for (int i = 0; i < 2; i++)
            #pragma unroll
            for (int j = 0; j < 4; j++)
                acc[i][j] = __builtin_amdgcn_mfma_f32_16x16x32_bf16(
                    af[i], bfr[j], acc[i][j], 0, 0, 0);
    }

    #pragma unroll
    for (int i = 0; i < 2; i++)
        #pragma unroll
        for (int j = 0; j < 4; j++)
            #pragma unroll
            for (int r = 0; r < 4; r++) {
                int row = bm + wm + i * 16 + quad * 4 + r;
                int col = bn + wn + j * 16 + l16;
                if (CF32)
                    ((float*)Cp)[(size_t)row * N + col] = acc[i][j][r];
                else
                    ((ushort_t*)Cp)[(size_t)row * N + col] = f2bf(acc[i][j][r]);
            }
}

// ---------------------------------------------------------------------------
// Fallback GEMM with fused fp32->bf16 staging (small-ws path; unchanged)
// ---------------------------------------------------------------------------
template<bool AF32, bool BF32, bool CF32>
__global__ __launch_bounds__(256) void gemm_bt(
    const void* __restrict__ Ap, const void* __restrict__ Bp,
    void* __restrict__ Cp, int M, int N, int K) {
    __shared__ ushort_t As[128][40];
    __shared__ ushort_t Bs[128][40];

    const int t    = threadIdx.x;
    const int wave = t >> 6;
    const int lane = t & 63;
    const int quad = lane >> 4;
    const int l16  = lane & 15;
    const int wm   = (wave >> 1) << 6;
    const int wn   = (wave & 1)  << 6;
    const int bm   = blockIdx.y * 128;
    const int bn   = blockIdx.x * 128;
    const int sr   = t >> 2;
    const int sc   = (t & 3) << 3;

    f32x4 acc[4][4];
    #pragma unroll
    for (int i = 0; i < 4; i++)
        #pragma unroll
        for (int j = 0; j < 4; j++) {
            f32x4 z = {0.f, 0.f, 0.f, 0.f};
            acc[i][j] = z;
        }

    for (int k0 = 0; k0 < K; k0 += 32) {
        __syncthreads();
        if (AF32) {
            const float* A = (const float*)Ap;
            const float* p0 = &A[(size_t)(bm + sr) * K + k0 + sc];
            const float* p1 = &A[(size_t)(bm + sr + 64) * K + k0 + sc];
            float4 a0 = *(const float4*)p0, a1 = *(const float4*)(p0 + 4);
            float4 b0 = *(const float4*)p1, b1 = *(const float4*)(p1 + 4);
            *(uint4*)&As[sr][sc] = make_uint4(
                pk_bf16(a0.x, a0.y), pk_bf16(a0.z, a0.w),
                pk_bf16(a1.x, a1.y), pk_bf16(a1.z, a1.w));
            *(uint4*)&As[sr + 64][sc] = make_uint4(
                pk_bf16(b0.x, b0.y), pk_bf16(b0.z, b0.w),
                pk_bf16(b1.x, b1.y), pk_bf16(b1.z, b1.w));
        } else {
            const ushort_t* A = (const ushort_t*)Ap;
            *(uint4*)&As[sr][sc]      = *(const uint4*)&A[(size_t)(bm + sr) * K + k0 + sc];
            *(uint4*)&As[sr + 64][sc] = *(const uint4*)&A[(size_t)(bm + sr + 64) * K + k0 + sc];
        }
        if (BF32) {
            const float* B = (const float*)Bp;
            const float* p0 = &B[(size_t)(bn + sr) * K + k0 + sc];
            const float* p1 = &B[(size_t)(bn + sr + 64) * K + k0 + sc];
            float4 a0 = *(const float4*)p0, a1 = *(const float4*)(p0 + 4);
            float4 b0 = *(const float4*)p1, b1 = *(const float4*)(p1 + 4);
            *(uint4*)&Bs[sr][sc] = make_uint4(
                pk_bf16(a0.x, a0.y), pk_bf16(a0.z, a0.w),
                pk_bf16(a1.x, a1.y), pk_bf16(a1.z, a1.w));
            *(uint4*)&Bs[sr + 64][sc] = make_uint4(
                pk_bf16(b0.x, b0.y), pk_bf16(b0.z, b0.w),
                pk_bf16(b1.x, b1.y), pk_bf16(b1.z, b1.w));
        } else {
            const ushort_t* B = (const ushort_t*)Bp;
            *(uint4*)&Bs[sr][sc]      = *(const uint4*)&B[(size_t)(bn + sr) * K + k0 + sc];
            *(uint4*)&Bs[sr + 64][sc] = *(const uint4*)&B[(size_t)(bn + sr + 64) * K + k0 + sc];
        }
        __syncthreads();

        bf16x8 af[4], bfr[4];
        #pragma unroll
        for (int i = 0; i < 4; i++)
            af[i] = *(const bf16x8*)&As[wm + i * 16 + l16][quad * 8];
        #pragma unroll
        for (int j = 0; j < 4; j++)
            bfr[j] = *(const bf16x8*)&Bs[wn + j * 16 + l16][quad * 8];

        #pragma unroll
        for (int i = 0; i < 4; i++)
            #pragma unroll
            for (int j = 0; j < 4; j++)
                acc[i][j] = __builtin_amdgcn_mfma_f32_16x16x32_bf16(
                    af[i], bfr[j], acc[i][j], 0, 0, 0);
    }

    #pragma unroll
    for (int i = 0; i < 4; i++)
        #pragma unroll
        for (int j = 0; j < 4; j++)
            #pragma unroll
            for (int r = 0; r < 4; r++) {
                int row = bm + wm + i * 16 + quad * 4 + r;
                int col = bn + wn + j * 16 + l16;
                if (CF32)
                    ((float*)Cp)[(size_t)row * N + col] = acc[i][j][r];
                else
                    ((ushort_t*)Cp)[(size_t)row * N + col] = f2bf(acc[i][j][r]);
            }
}

// ---------------------------------------------------------------------------
// RoPE in-place (unchanged)
// ---------------------------------------------------------------------------
__global__ __launch_bounds__(256) void rope_kernel(
    ushort_t* __restrict__ qkv, const float* __restrict__ cs,
    const float* __restrict__ sn) {
    int idx = blockIdx.x * 256 + threadIdx.x;
    if (idx >= S_LEN * (NQH + NKVH)) return;
    int s  = idx / (NQH + NKVH);
    int hh = idx - s * (NQH + NKVH);

    ushort_t* p = &qkv[(size_t)s * QKV_O + hh * HD];
    const uint4* p4 = (const uint4*)p;
    float v[HD], c[HD], sv[HD];
    #pragma unroll
    for (int b = 0; b < 8; b++) unpack8(&v[b * 8], p4[b]);
    const float4* c4 = (const float4*)&cs[s * HD];
    const float4* s4 = (const float4*)&sn[s * HD];
    #pragma unroll
    for (int b = 0; b < 16; b++) {
        ((float4*)c)[b]  = c4[b];
        ((float4*)sv)[b] = s4[b];
    }
    float o[HD];
    #pragma unroll
    for (int d = 0; d < 32; d++) {
        o[d]      = v[d] * c[d]           - v[d + 32] * sv[d];
        o[d + 32] = v[d + 32] * c[d + 32] + v[d]      * sv[d + 32];
    }
    unsigned int* pw = (unsigned int*)p;
    #pragma unroll
    for (int d = 0; d < HD; d += 2)
        pw[d >> 1] = pk_bf16(o[d], o[d + 1]);
}

// ---------------------------------------------------------------------------
// attn_v3: S^T-orientation MFMA flash attention with COMPLEMENTARY Q-TILE
// PAIRING for causal load balance. Block (p,h) handles deep 64-row Q-tile
// D=31-p and shallow tile S=p; each wave owns 16 deep rows (mi=0) + 16
// shallow rows (mi=1). Deep active for all 32-p K-tiles, shallow for p+1
// -> uniform 33 m-tile-units of compute per block (round-8 occupancy 12.8%
// showed half the CUs idling behind the 32-iter deepest blocks).
// Shallow-skip is block-uniform; barriers unchanged; p=0 dispatches first.
// ---------------------------------------------------------------------------
__global__ __launch_bounds__(256) void attn_v3(
    const ushort_t* __restrict__ qkv, ushort_t* __restrict__ O) {
    const int bx   = blockIdx.x;            // 512 blocks
    const int h    = bx & 31;               // head
    const int p    = bx >> 5;               // pair index 0..15 (p=0 heaviest)
    const int kvh  = h >> 2;                // GQA group size 4
    const int q0d  = (31 - p) * 64;         // deep Q-tile base row
    const int q0s  = p * 64;                // shallow Q-tile base row
    const int tid  = threadIdx.x;
    const int wave = tid >> 6;
    const int lane = tid & 63;
    const int quad = lane >> 4;
    const int l16  = lane & 15;

    __shared__ __align__(16) ushort_t Ks[64][72];      // K tile [kcol][d]    9.2 KB
    __shared__ __align__(16) ushort_t Vt[64][72];      // V^T rot [d][kcol']  9.2 KB
    __shared__ __align__(16) ushort_t Pl[4][32][72];   // per-wave P [qrow][kcol] 18.4 KB

    const int rowbase0 = q0d + wave * 16;
    const int rowbase1 = q0s + wave * 16;

    // Q B-frags (lane l16 = qrow), pre-scaled by 1/8 (exact in bf16)
    bf16x8 bq[2][2];
    #pragma unroll
    for (int mi = 0; mi < 2; mi++) {
        const int rb = (mi == 0) ? rowbase0 : rowbase1;
        #pragma unroll
        for (int ks = 0; ks < 2; ks++) {
            uint4 u = *(const uint4*)&qkv[(size_t)(rb + l16) * QKV_O
                                          + h * HD + ks * 32 + quad * 8];
            float f[8]; unpack8(f, u);
            uint4 w = make_uint4(
                pk_bf16(f[0] * 0.125f, f[1] * 0.125f),
                pk_bf16(f[2] * 0.125f, f[3] * 0.125f),
                pk_bf16(f[4] * 0.125f, f[5] * 0.125f),
                pk_bf16(f[6] * 0.125f, f[7] * 0.125f));
            __builtin_memcpy(&bq[mi][ks], &w, 16);
        }
    }

    bf16x8 ones;
    #pragma unroll
    for (int e = 0; e < 8; e++) ones[e] = (__bf16)1.0f;

    f32x4 acc_o[2][4];
    f32x4 acc_l[2];
    #pragma unroll
    for (int mi = 0; mi < 2; mi++) {
        f32x4 z = {0.f, 0.f, 0.f, 0.f};
        acc_l[mi] = z;
        #pragma unroll
        for (int n = 0; n < 4; n++) acc_o[mi][n] = z;
    }

    const int nt = 32 - p;               // K tiles for the deep tile
    const int sr = tid >> 2;             // staging kcol 0..63
    const int sc = (tid & 3) << 4;       // staging d {0,16,32,48}

    for (int t = 0; t < nt; t++) {
        const int j0 = t * 64;
        __syncthreads();
        {   // ---- stage K row-major (b128), V transposed+rotated ----
            const ushort_t* kp = &qkv[(size_t)(j0 + sr) * QKV_O + K_COL + kvh * HD + sc];
            *(uint4*)&Ks[sr][sc]     = *(const uint4*)kp;
            *(uint4*)&Ks[sr][sc + 8] = *(const uint4*)(kp + 8);
            const ushort_t* vp = &qkv[(size_t)(j0 + sr) * QKV_O + V_COL + kvh * HD + sc];
            ushort_t tmp[16];
            *(uint4*)&tmp[0] = *(const uint4*)vp;
            *(uint4*)&tmp[8] = *(const uint4*)(vp + 8);
            #pragma unroll
            for (int e = 0; e < 16; e++) {
                int d = sc + e;
                Vt[d][(sr + 8 * (d >> 3)) & 63] = tmp[e];
            }
        }
        __syncthreads();

        const bool sact = (t <= p);          // shallow active (block-uniform)
        const int  mcnt = sact ? 2 : 1;

        // ---- S^T = K·Q^T ----
        f32x4 st[2][4];
        #pragma unroll
        for (int mi = 0; mi < 2; mi++)
            #pragma unroll
            for (int nk = 0; nk < 4; nk++) {
                f32x4 z = {0.f, 0.f, 0.f, 0.f};
                st[mi][nk] = z;
            }
        #pragma unroll
        for (int ks = 0; ks < 2; ks++) {
            bf16x8 ak[4];
            #pragma unroll
            for (int nk = 0; nk < 4; nk++)
                ak[nk] = *(const bf16x8*)&Ks[nk * 16 + l16][ks * 32 + quad * 8];
            for (int mi = 0; mi < mcnt; mi++)
                #pragma unroll
                for (int nk = 0; nk < 4; nk++)
                    st[mi][nk] = __builtin_amdgcn_mfma_f32_16x16x32_bf16(
                        ak[nk], bq[mi][ks], st[mi][nk], 0, 0, 0);
        }

        // ---- exp + causal mask, b64 P stores ----
        for (int mi = 0; mi < mcnt; mi++) {
            const bool diag = (mi == 0) ? (t == nt - 1) : (t == p);
            const int qrow = ((mi == 0) ? rowbase0 : rowbase1) + l16;
            #pragma unroll
            for (int nk = 0; nk < 4; nk++) {
                const int kc0 = j0 + nk * 16 + quad * 4;
                float pv[4];
                #pragma unroll
                for (int r = 0; r < 4; r++) {
                    float e = __expf(st[mi][nk][r]);
                    pv[r] = (diag && (kc0 + r > qrow)) ? 0.f : e;
                }
                uint2 w2 = make_uint2(pk_bf16(pv[0], pv[1]), pk_bf16(pv[2], pv[3]));
                *(uint2*)&Pl[wave][mi * 16 + l16][nk * 16 + quad * 4] = w2;
            }
        }

        // ---- l += P·1 ; O += P·V ----
        #pragma unroll
        for (int ksp = 0; ksp < 2; ksp++) {
            bf16x8 bv[4];
            #pragma unroll
            for (int nd = 0; nd < 4; nd++) {
                const int d = nd * 16 + l16;
                bv[nd] = *(const bf16x8*)&Vt[d][(ksp * 32 + quad * 8 + 8 * (d >> 3)) & 63];
            }
            for (int mi = 0; mi < mcnt; mi++) {
                bf16x8 ap = *(const bf16x8*)&Pl[wave][mi * 16 + l16][ksp * 32 + quad * 8];
                acc_l[mi] = __builtin_amdgcn_mfma_f32_16x16x32_bf16(
                    ap, ones, acc_l[mi], 0, 0, 0);
                #pragma unroll
                for (int nd = 0; nd < 4; nd++)
                    acc_o[mi][nd] = __builtin_amdgcn_mfma_f32_16x16x32_bf16(
                        ap, bv[nd], acc_o[mi][nd], 0, 0, 0);
            }
        }
    }

    // ---- epilogue: O / l  (C-layout: local qrow=quad*4+r, d=nd*16+l16) ----
    #pragma unroll
    for (int mi = 0; mi < 2; mi++) {
        const int rb = (mi == 0) ? rowbase0 : rowbase1;
        float inv[4];
        #pragma unroll
        for (int r = 0; r < 4; r++) inv[r] = 1.0f / acc_l[mi][r];
        #pragma unroll
        for (int nd = 0; nd < 4; nd++)
            #pragma unroll
            for (int r = 0; r < 4; r++) {
                int row = rb + quad * 4 + r;
                int col = h * HD + nd * 16 + l16;
                O[(size_t)row * (NQH * HD) + col] = f2bf(acc_o[mi][nd][r] * inv[r]);
            }
    }
}

// ---------------------------------------------------------------------------
extern "C" void kernel_launch(void* const* d_in, const int* in_sizes, int n_in,
                              void* d_out, int out_size, void* d_ws, size_t ws_size,
                              hipStream_t stream) {
    const float* x     = (const float*)d_in[0];  // [2048][2048] fp32
    const float* cosp  = (const float*)d_in[1];  // [2048][64]   fp32
    const float* sinp  = (const float*)d_in[2];  // [2048][64]   fp32
    const float* w_qkv = (const float*)d_in[3];  // [3072][2048] fp32
    const float* w_out = (const float*)d_in[4];  // [2048][2048] fp32
    float* out = (float*)d_out;                  // [2048][2048] fp32

    const size_t NQKV = (size_t)S_LEN * QKV_O;   // 6291456
    const size_t NH2  = (size_t)S_LEN * HID;     // 4194304
    const size_t need = 2 * (NQKV + NH2) * sizeof(ushort_t);  // 41.9 MB

    ushort_t* qkv = (ushort_t*)d_ws;             // bf16 [2048][3072]

    if (ws_size >= need) {
        ushort_t* x_bf    = qkv + NQKV;
        ushort_t* attnO   = x_bf;                // disjoint lifetimes
        ushort_t* wqkv_bf = x_bf + NH2;
        ushort_t* wout_bf = wqkv_bf + NQKV;

        convert3<<<XN8 / 256 + QN8 / 256 + ON8 / 256, 256, 0, stream>>>(
            x, w_qkv, w_out, x_bf, wqkv_bf, wout_bf);

        dim3 g1(QKV_O / 128, S_LEN / 64);
        gemm64<false><<<g1, 256, 0, stream>>>(x_bf, wqkv_bf, qkv, S_LEN, QKV_O, HID);

        int rope_threads = S_LEN * (NQH + NKVH);
        rope_kernel<<<(rope_threads + 255) / 256, 256, 0, stream>>>(qkv, cosp, sinp);

        attn_v3<<<16 * NQH, 256, 0, stream>>>(qkv, attnO);

        dim3 g2(HID / 128, S_LEN / 64);
        gemm64<true><<<g2, 256, 0, stream>>>(attnO, wout_bf, out, S_LEN, HID, HID);
    } else {
        ushort_t* attnO = qkv + NQKV;

        dim3 g1(QKV_O / 128, S_LEN / 128);
        gemm_bt<true, true, false><<<g1, 256, 0, stream>>>(x, w_qkv, qkv, S_LEN, QKV_O, HID);

        int rope_threads = S_LEN * (NQH + NKVH);
        rope_kernel<<<(rope_threads + 255) / 256, 256, 0, stream>>>(qkv, cosp, sinp);

        attn_v3<<<16 * NQH, 256, 0, stream>>>(qkv, attnO);

        dim3 g2(HID / 128, S_LEN / 128);
        gemm_bt<false, true, true><<<g2, 256, 0, stream>>>(attnO, w_out, out, S_LEN, HID, HID);
    }
}

// Round 10
// 233.335 us; speedup vs baseline: 2.1277x; 2.1277x over previous
//
#include <hip/hip_runtime.h>
#include <hip/hip_bf16.h>
#include <stdint.h>

// Problem constants (B=1). I/O dtype: fp32. Internals bf16 (MFMA path).
#define S_LEN 2048
#define HID   2048
#define NQH   32
#define NKVH  8
#define HD    64
#define QKV_O 3072      // (32 + 2*8) * 64
#define K_COL 2048      // col offset of K block in qkv row
#define V_COL 2560      // col offset of V block in qkv row

typedef unsigned short ushort_t;
typedef __bf16 bf16x8 __attribute__((ext_vector_type(8)));
typedef float  f32x4  __attribute__((ext_vector_type(4)));

#define GLB(p) ((const __attribute__((address_space(1))) void*)(p))
#define LDSP(p) ((__attribute__((address_space(3))) void*)(p))

__device__ __forceinline__ ushort_t f2bf(float f) {
    unsigned int x = __float_as_uint(f);
    unsigned int r = (x + 0x7fffu + ((x >> 16) & 1u)) >> 16;   // RNE
    return (ushort_t)r;
}
__device__ __forceinline__ unsigned int pk_bf16(float a, float b) {
    __hip_bfloat162 h = __float22bfloat162_rn(make_float2(a, b));
    unsigned int r;
    __builtin_memcpy(&r, &h, 4);
    return r;
}
__device__ __forceinline__ void unpack8(float* dst, uint4 u) {
    dst[0] = __uint_as_float(u.x << 16); dst[1] = __uint_as_float(u.x & 0xffff0000u);
    dst[2] = __uint_as_float(u.y << 16); dst[3] = __uint_as_float(u.y & 0xffff0000u);
    dst[4] = __uint_as_float(u.z << 16); dst[5] = __uint_as_float(u.z & 0xffff0000u);
    dst[6] = __uint_as_float(u.w << 16); dst[7] = __uint_as_float(u.w & 0xffff0000u);
}

// ---------------------------------------------------------------------------
// convert3: fp32 -> bf16 for x, w_qkv, w_out (unchanged)
// ---------------------------------------------------------------------------
#define XN8 (S_LEN * HID / 8)          // 524288
#define QN8 (QKV_O * HID / 8)          // 786432
#define ON8 (HID * HID / 8)            // 524288

__global__ __launch_bounds__(256) void convert3(
    const float* __restrict__ x, const float* __restrict__ wq,
    const float* __restrict__ wo, ushort_t* __restrict__ xb,
    ushort_t* __restrict__ wqb, ushort_t* __restrict__ wob) {
    int i = blockIdx.x * 256 + threadIdx.x;
    const float* s; ushort_t* d; int off;
    if (i < XN8)            { s = x;  d = xb;  off = i; }
    else if (i < XN8 + QN8) { s = wq; d = wqb; off = i - XN8; }
    else                    { s = wo; d = wob; off = i - XN8 - QN8; }
    const float4* sp = (const float4*)s + (size_t)off * 2;
    float4 a = sp[0], b = sp[1];
    *(uint4*)(d + (size_t)off * 8) = make_uint4(
        pk_bf16(a.x, a.y), pk_bf16(a.z, a.w),
        pk_bf16(b.x, b.y), pk_bf16(b.z, b.w));
}

// ---------------------------------------------------------------------------
// gemm64: pure-bf16 GEMM, 64x128 (MxN) tile, BK=32 (unchanged from round 8)
// ---------------------------------------------------------------------------
template<bool CF32>
__global__ __launch_bounds__(256) void gemm64(
    const ushort_t* __restrict__ A, const ushort_t* __restrict__ Bt,
    void* __restrict__ Cp, int M, int N, int K) {
    __shared__ ushort_t As[64][32];
    __shared__ ushort_t Bs[128][32];

    const int t    = threadIdx.x;
    const int wave = t >> 6;
    const int lane = t & 63;
    const int quad = lane >> 4;
    const int l16  = lane & 15;
    const int wm   = (wave >> 1) << 5;
    const int wn   = (wave & 1)  << 6;
    const int bm   = blockIdx.y * 64;
    const int bn   = blockIdx.x * 128;
    const int lrow = lane >> 2;
    const int lcol = (lane & 3) << 3;

    f32x4 acc[2][4];
    #pragma unroll
    for (int i = 0; i < 2; i++)
        #pragma unroll
        for (int j = 0; j < 4; j++) {
            f32x4 z = {0.f, 0.f, 0.f, 0.f};
            acc[i][j] = z;
        }

    const ushort_t* a0 = &A[(size_t)(bm + wave * 16 + lrow) * K + lcol];
    const ushort_t* b0 = &Bt[(size_t)(bn + wave * 32 + lrow) * K + lcol];
    const size_t r16 = (size_t)16 * K;

    for (int k0 = 0; k0 < K; k0 += 32) {
        __syncthreads();
        __builtin_amdgcn_global_load_lds(GLB(a0 + k0),       LDSP(&As[wave * 16][0]),      16, 0, 0);
        __builtin_amdgcn_global_load_lds(GLB(b0 + k0),       LDSP(&Bs[wave * 32][0]),      16, 0, 0);
        __builtin_amdgcn_global_load_lds(GLB(b0 + k0 + r16), LDSP(&Bs[wave * 32 + 16][0]), 16, 0, 0);
        __syncthreads();

        bf16x8 af[2], bfr[4];
        #pragma unroll
        for (int i = 0; i < 2; i++)
            af[i] = *(const bf16x8*)&As[wm + i * 16 + l16][quad * 8];
        #pragma unroll
        for (int j = 0; j < 4; j++)
            bfr[j] = *(const bf16x8*)&Bs[wn + j * 16 + l16][quad * 8];

        #pragma unroll
        for (int i = 0; i < 2; i++)
            #pragma unroll
            for (int j = 0; j < 4; j++)
                acc[i][j] = __builtin_amdgcn_mfma_f32_16x16x32_bf16(
                    af[i], bfr[j], acc[i][j], 0, 0, 0);
    }

    #pragma unroll
    for (int i = 0; i < 2; i++)
        #pragma unroll
        for (int j = 0; j < 4; j++)
            #pragma unroll
            for (int r = 0; r < 4; r++) {
                int row = bm + wm + i * 16 + quad * 4 + r;
                int col = bn + wn + j * 16 + l16;
                if (CF32)
                    ((float*)Cp)[(size_t)row * N + col] = acc[i][j][r];
                else
                    ((ushort_t*)Cp)[(size_t)row * N + col] = f2bf(acc[i][j][r]);
            }
}

// ---------------------------------------------------------------------------
// Fallback GEMM with fused fp32->bf16 staging (small-ws path; unchanged)
// ---------------------------------------------------------------------------
template<bool AF32, bool BF32, bool CF32>
__global__ __launch_bounds__(256) void gemm_bt(
    const void* __restrict__ Ap, const void* __restrict__ Bp,
    void* __restrict__ Cp, int M, int N, int K) {
    __shared__ ushort_t As[128][40];
    __shared__ ushort_t Bs[128][40];

    const int t    = threadIdx.x;
    const int wave = t >> 6;
    const int lane = t & 63;
    const int quad = lane >> 4;
    const int l16  = lane & 15;
    const int wm   = (wave >> 1) << 6;
    const int wn   = (wave & 1)  << 6;
    const int bm   = blockIdx.y * 128;
    const int bn   = blockIdx.x * 128;
    const int sr   = t >> 2;
    const int sc   = (t & 3) << 3;

    f32x4 acc[4][4];
    #pragma unroll
    for (int i = 0; i < 4; i++)
        #pragma unroll
        for (int j = 0; j < 4; j++) {
            f32x4 z = {0.f, 0.f, 0.f, 0.f};
            acc[i][j] = z;
        }

    for (int k0 = 0; k0 < K; k0 += 32) {
        __syncthreads();
        if (AF32) {
            const float* A = (const float*)Ap;
            const float* p0 = &A[(size_t)(bm + sr) * K + k0 + sc];
            const float* p1 = &A[(size_t)(bm + sr + 64) * K + k0 + sc];
            float4 a0 = *(const float4*)p0, a1 = *(const float4*)(p0 + 4);
            float4 b0 = *(const float4*)p1, b1 = *(const float4*)(p1 + 4);
            *(uint4*)&As[sr][sc] = make_uint4(
                pk_bf16(a0.x, a0.y), pk_bf16(a0.z, a0.w),
                pk_bf16(a1.x, a1.y), pk_bf16(a1.z, a1.w));
            *(uint4*)&As[sr + 64][sc] = make_uint4(
                pk_bf16(b0.x, b0.y), pk_bf16(b0.z, b0.w),
                pk_bf16(b1.x, b1.y), pk_bf16(b1.z, b1.w));
        } else {
            const ushort_t* A = (const ushort_t*)Ap;
            *(uint4*)&As[sr][sc]      = *(const uint4*)&A[(size_t)(bm + sr) * K + k0 + sc];
            *(uint4*)&As[sr + 64][sc] = *(const uint4*)&A[(size_t)(bm + sr + 64) * K + k0 + sc];
        }
        if (BF32) {
            const float* B = (const float*)Bp;
            const float* p0 = &B[(size_t)(bn + sr) * K + k0 + sc];
            const float* p1 = &B[(size_t)(bn + sr + 64) * K + k0 + sc];
            float4 a0 = *(const float4*)p0, a1 = *(const float4*)(p0 + 4);
            float4 b0 = *(const float4*)p1, b1 = *(const float4*)(p1 + 4);
            *(uint4*)&Bs[sr][sc] = make_uint4(
                pk_bf16(a0.x, a0.y), pk_bf16(a0.z, a0.w),
                pk_bf16(a1.x, a1.y), pk_bf16(a1.z, a1.w));
            *(uint4*)&Bs[sr + 64][sc] = make_uint4(
                pk_bf16(b0.x, b0.y), pk_bf16(b0.z, b0.w),
                pk_bf16(b1.x, b1.y), pk_bf16(b1.z, b1.w));
        } else {
            const ushort_t* B = (const ushort_t*)Bp;
            *(uint4*)&Bs[sr][sc]      = *(const uint4*)&B[(size_t)(bn + sr) * K + k0 + sc];
            *(uint4*)&Bs[sr + 64][sc] = *(const uint4*)&B[(size_t)(bn + sr + 64) * K + k0 + sc];
        }
        __syncthreads();

        bf16x8 af[4], bfr[4];
        #pragma unroll
        for (int i = 0; i < 4; i++)
            af[i] = *(const bf16x8*)&As[wm + i * 16 + l16][quad * 8];
        #pragma unroll
        for (int j = 0; j < 4; j++)
            bfr[j] = *(const bf16x8*)&Bs[wn + j * 16 + l16][quad * 8];

        #pragma unroll
        for (int i = 0; i < 4; i++)
            #pragma unroll
            for (int j = 0; j < 4; j++)
                acc[i][j] = __builtin_amdgcn_mfma_f32_16x16x32_bf16(
                    af[i], bfr[j], acc[i][j], 0, 0, 0);
    }

    #pragma unroll
    for (int i = 0; i < 4; i++)
        #pragma unroll
        for (int j = 0; j < 4; j++)
            #pragma unroll
            for (int r = 0; r < 4; r++) {
                int row = bm + wm + i * 16 + quad * 4 + r;
                int col = bn + wn + j * 16 + l16;
                if (CF32)
                    ((float*)Cp)[(size_t)row * N + col] = acc[i][j][r];
                else
                    ((ushort_t*)Cp)[(size_t)row * N + col] = f2bf(acc[i][j][r]);
            }
}

// ---------------------------------------------------------------------------
// RoPE in-place (unchanged)
// ---------------------------------------------------------------------------
__global__ __launch_bounds__(256) void rope_kernel(
    ushort_t* __restrict__ qkv, const float* __restrict__ cs,
    const float* __restrict__ sn) {
    int idx = blockIdx.x * 256 + threadIdx.x;
    if (idx >= S_LEN * (NQH + NKVH)) return;
    int s  = idx / (NQH + NKVH);
    int hh = idx - s * (NQH + NKVH);

    ushort_t* p = &qkv[(size_t)s * QKV_O + hh * HD];
    const uint4* p4 = (const uint4*)p;
    float v[HD], c[HD], sv[HD];
    #pragma unroll
    for (int b = 0; b < 8; b++) unpack8(&v[b * 8], p4[b]);
    const float4* c4 = (const float4*)&cs[s * HD];
    const float4* s4 = (const float4*)&sn[s * HD];
    #pragma unroll
    for (int b = 0; b < 16; b++) {
        ((float4*)c)[b]  = c4[b];
        ((float4*)sv)[b] = s4[b];
    }
    float o[HD];
    #pragma unroll
    for (int d = 0; d < 32; d++) {
        o[d]      = v[d] * c[d]           - v[d + 32] * sv[d];
        o[d + 32] = v[d + 32] * c[d + 32] + v[d]      * sv[d + 32];
    }
    unsigned int* pw = (unsigned int*)p;
    #pragma unroll
    for (int d = 0; d < HD; d += 2)
        pw[d >> 1] = pk_bf16(o[d], o[d + 1]);
}

// ---------------------------------------------------------------------------
// attn_v4: complementary Q-tile pairing (round-9 schedule) with COMPILE-TIME
// mi indexing. Round-9's runtime `mi < mcnt` bounds made st/bq/acc_o
// dynamically-indexed register arrays -> scratch demotion (MfmaUtil 12->2.5%).
// Here every mi loop is `#pragma unroll` over [0,2) with a block-uniform
// `if (mi == 1 && !sact) continue;` — after unroll, mi is a literal in all
// indices; the skip is a uniform branch around straight-line code.
// Schedule: block (p,h) = deep tile D=31-p (all 32-p K-tiles) + shallow tile
// S=p (first p+1 K-tiles) -> uniform 33 m-tile-units/block. p=0 first.
// ---------------------------------------------------------------------------
__global__ __launch_bounds__(256) void attn_v4(
    const ushort_t* __restrict__ qkv, ushort_t* __restrict__ O) {
    const int bx   = blockIdx.x;            // 512 blocks
    const int h    = bx & 31;               // head
    const int p    = bx >> 5;               // pair index 0..15 (p=0 heaviest)
    const int kvh  = h >> 2;                // GQA group size 4
    const int q0d  = (31 - p) * 64;         // deep Q-tile base row
    const int q0s  = p * 64;                // shallow Q-tile base row
    const int tid  = threadIdx.x;
    const int wave = tid >> 6;
    const int lane = tid & 63;
    const int quad = lane >> 4;
    const int l16  = lane & 15;

    __shared__ __align__(16) ushort_t Ks[64][72];      // K tile [kcol][d]    9.2 KB
    __shared__ __align__(16) ushort_t Vt[64][72];      // V^T rot [d][kcol']  9.2 KB
    __shared__ __align__(16) ushort_t Pl[4][32][72];   // per-wave P [qrow][kcol] 18.4 KB

    const int rowbase0 = q0d + wave * 16;   // mi=0 (deep)
    const int rowbase1 = q0s + wave * 16;   // mi=1 (shallow)

    // Q B-frags (lane l16 = qrow), pre-scaled by 1/8 (exact in bf16)
    bf16x8 bq[2][2];
    #pragma unroll
    for (int mi = 0; mi < 2; mi++) {
        const int rb = (mi == 0) ? rowbase0 : rowbase1;
        #pragma unroll
        for (int ks = 0; ks < 2; ks++) {
            uint4 u = *(const uint4*)&qkv[(size_t)(rb + l16) * QKV_O
                                          + h * HD + ks * 32 + quad * 8];
            float f[8]; unpack8(f, u);
            uint4 w = make_uint4(
                pk_bf16(f[0] * 0.125f, f[1] * 0.125f),
                pk_bf16(f[2] * 0.125f, f[3] * 0.125f),
                pk_bf16(f[4] * 0.125f, f[5] * 0.125f),
                pk_bf16(f[6] * 0.125f, f[7] * 0.125f));
            __builtin_memcpy(&bq[mi][ks], &w, 16);
        }
    }

    bf16x8 ones;
    #pragma unroll
    for (int e = 0; e < 8; e++) ones[e] = (__bf16)1.0f;

    f32x4 acc_o[2][4];
    f32x4 acc_l[2];
    #pragma unroll
    for (int mi = 0; mi < 2; mi++) {
        f32x4 z = {0.f, 0.f, 0.f, 0.f};
        acc_l[mi] = z;
        #pragma unroll
        for (int n = 0; n < 4; n++) acc_o[mi][n] = z;
    }

    const int nt = 32 - p;               // K tiles for the deep tile
    const int sr = tid >> 2;             // staging kcol 0..63
    const int sc = (tid & 3) << 4;       // staging d {0,16,32,48}

    for (int t = 0; t < nt; t++) {
        const int j0 = t * 64;
        __syncthreads();
        {   // ---- stage K row-major (b128), V transposed+rotated ----
            const ushort_t* kp = &qkv[(size_t)(j0 + sr) * QKV_O + K_COL + kvh * HD + sc];
            *(uint4*)&Ks[sr][sc]     = *(const uint4*)kp;
            *(uint4*)&Ks[sr][sc + 8] = *(const uint4*)(kp + 8);
            const ushort_t* vp = &qkv[(size_t)(j0 + sr) * QKV_O + V_COL + kvh * HD + sc];
            ushort_t tmp[16];
            *(uint4*)&tmp[0] = *(const uint4*)vp;
            *(uint4*)&tmp[8] = *(const uint4*)(vp + 8);
            #pragma unroll
            for (int e = 0; e < 16; e++) {
                int d = sc + e;
                Vt[d][(sr + 8 * (d >> 3)) & 63] = tmp[e];
            }
        }
        __syncthreads();

        const bool sact = (t <= p);          // shallow active (block-uniform)

        // ---- S^T = K·Q^T ----
        f32x4 st[2][4];
        #pragma unroll
        for (int mi = 0; mi < 2; mi++)
            #pragma unroll
            for (int nk = 0; nk < 4; nk++) {
                f32x4 z = {0.f, 0.f, 0.f, 0.f};
                st[mi][nk] = z;
            }
        #pragma unroll
        for (int ks = 0; ks < 2; ks++) {
            bf16x8 ak[4];
            #pragma unroll
            for (int nk = 0; nk < 4; nk++)
                ak[nk] = *(const bf16x8*)&Ks[nk * 16 + l16][ks * 32 + quad * 8];
            #pragma unroll
            for (int mi = 0; mi < 2; mi++) {
                if (mi == 1 && !sact) continue;       // uniform, post-unroll
                #pragma unroll
                for (int nk = 0; nk < 4; nk++)
                    st[mi][nk] = __builtin_amdgcn_mfma_f32_16x16x32_bf16(
                        ak[nk], bq[mi][ks], st[mi][nk], 0, 0, 0);
            }
        }

        // ---- exp + causal mask, b64 P stores ----
        #pragma unroll
        for (int mi = 0; mi < 2; mi++) {
            if (mi == 1 && !sact) continue;           // uniform, post-unroll
            const bool diag = (mi == 0) ? (t == nt - 1) : (t == p);
            const int qrow = ((mi == 0) ? rowbase0 : rowbase1) + l16;
            #pragma unroll
            for (int nk = 0; nk < 4; nk++) {
                const int kc0 = j0 + nk * 16 + quad * 4;
                float pv[4];
                #pragma unroll
                for (int r = 0; r < 4; r++) {
                    float e = __expf(st[mi][nk][r]);
                    pv[r] = (diag && (kc0 + r > qrow)) ? 0.f : e;
                }
                uint2 w2 = make_uint2(pk_bf16(pv[0], pv[1]), pk_bf16(pv[2], pv[3]));
                *(uint2*)&Pl[wave][mi * 16 + l16][nk * 16 + quad * 4] = w2;
            }
        }

        // ---- l += P·1 ; O += P·V ----
        #pragma unroll
        for (int ksp = 0; ksp < 2; ksp++) {
            bf16x8 bv[4];
            #pragma unroll
            for (int nd = 0; nd < 4; nd++) {
                const int d = nd * 16 + l16;
                bv[nd] = *(const bf16x8*)&Vt[d][(ksp * 32 + quad * 8 + 8 * (d >> 3)) & 63];
            }
            #pragma unroll
            for (int mi = 0; mi < 2; mi++) {
                if (mi == 1 && !sact) continue;       // uniform, post-unroll
                bf16x8 ap = *(const bf16x8*)&Pl[wave][mi * 16 + l16][ksp * 32 + quad * 8];
                acc_l[mi] = __builtin_amdgcn_mfma_f32_16x16x32_bf16(
                    ap, ones, acc_l[mi], 0, 0, 0);
                #pragma unroll
                for (int nd = 0; nd < 4; nd++)
                    acc_o[mi][nd] = __builtin_amdgcn_mfma_f32_16x16x32_bf16(
                        ap, bv[nd], acc_o[mi][nd], 0, 0, 0);
            }
        }
    }

    // ---- epilogue: O / l  (C-layout: local qrow=quad*4+r, d=nd*16+l16) ----
    #pragma unroll
    for (int mi = 0; mi < 2; mi++) {
        const int rb = (mi == 0) ? rowbase0 : rowbase1;
        float inv[4];
        #pragma unroll
        for (int r = 0; r < 4; r++) inv[r] = 1.0f / acc_l[mi][r];
        #pragma unroll
        for (int nd = 0; nd < 4; nd++)
            #pragma unroll
            for (int r = 0; r < 4; r++) {
                int row = rb + quad * 4 + r;
                int col = h * HD + nd * 16 + l16;
                O[(size_t)row * (NQH * HD) + col] = f2bf(acc_o[mi][nd][r] * inv[r]);
            }
    }
}

// ---------------------------------------------------------------------------
extern "C" void kernel_launch(void* const* d_in, const int* in_sizes, int n_in,
                              void* d_out, int out_size, void* d_ws, size_t ws_size,
                              hipStream_t stream) {
    const float* x     = (const float*)d_in[0];  // [2048][2048] fp32
    const float* cosp  = (const float*)d_in[1];  // [2048][64]   fp32
    const float* sinp  = (const float*)d_in[2];  // [2048][64]   fp32
    const float* w_qkv = (const float*)d_in[3];  // [3072][2048] fp32
    const float* w_out = (const float*)d_in[4];  // [2048][2048] fp32
    float* out = (float*)d_out;                  // [2048][2048] fp32

    const size_t NQKV = (size_t)S_LEN * QKV_O;   // 6291456
    const size_t NH2  = (size_t)S_LEN * HID;     // 4194304
    const size_t need = 2 * (NQKV + NH2) * sizeof(ushort_t);  // 41.9 MB

    ushort_t* qkv = (ushort_t*)d_ws;             // bf16 [2048][3072]

    if (ws_size >= need) {
        ushort_t* x_bf    = qkv + NQKV;
        ushort_t* attnO   = x_bf;                // disjoint lifetimes
        ushort_t* wqkv_bf = x_bf + NH2;
        ushort_t* wout_bf = wqkv_bf + NQKV;

        convert3<<<XN8 / 256 + QN8 / 256 + ON8 / 256, 256, 0, stream>>>(
            x, w_qkv, w_out, x_bf, wqkv_bf, wout_bf);

        dim3 g1(QKV_O / 128, S_LEN / 64);
        gemm64<false><<<g1, 256, 0, stream>>>(x_bf, wqkv_bf, qkv, S_LEN, QKV_O, HID);

        int rope_threads = S_LEN * (NQH + NKVH);
        rope_kernel<<<(rope_threads + 255) / 256, 256, 0, stream>>>(qkv, cosp, sinp);

        attn_v4<<<16 * NQH, 256, 0, stream>>>(qkv, attnO);

        dim3 g2(HID / 128, S_LEN / 64);
        gemm64<true><<<g2, 256, 0, stream>>>(attnO, wout_bf, out, S_LEN, HID, HID);
    } else {
        ushort_t* attnO = qkv + NQKV;

        dim3 g1(QKV_O / 128, S_LEN / 128);
        gemm_bt<true, true, false><<<g1, 256, 0, stream>>>(x, w_qkv, qkv, S_LEN, QKV_O, HID);

        int rope_threads = S_LEN * (NQH + NKVH);
        rope_kernel<<<(rope_threads + 255) / 256, 256, 0, stream>>>(qkv, cosp, sinp);

        attn_v4<<<16 * NQH, 256, 0, stream>>>(qkv, attnO);

        dim3 g2(HID / 128, S_LEN / 128);
        gemm_bt<false, true, true><<<g2, 256, 0, stream>>>(attnO, w_out, out, S_LEN, HID, HID);
    }
}

// Round 11
// 217.539 us; speedup vs baseline: 2.2822x; 1.0726x over previous
//
#include <hip/hip_runtime.h>
#include <hip/hip_bf16.h>
#include <stdint.h>

// Problem constants (B=1). I/O dtype: fp32. Internals bf16 (MFMA path).
#define S_LEN 2048
#define HID   2048
#define NQH   32
#define NKVH  8
#define HD    64
#define QKV_O 3072      // (32 + 2*8) * 64
#define K_COL 2048      // col offset of K block in qkv row
#define V_COL 2560      // col offset of V block in qkv row

typedef unsigned short ushort_t;
typedef __bf16 bf16x8 __attribute__((ext_vector_type(8)));
typedef float  f32x4  __attribute__((ext_vector_type(4)));

#define GLB(p) ((const __attribute__((address_space(1))) void*)(p))
#define LDSP(p) ((__attribute__((address_space(3))) void*)(p))

__device__ __forceinline__ ushort_t f2bf(float f) {
    unsigned int x = __float_as_uint(f);
    unsigned int r = (x + 0x7fffu + ((x >> 16) & 1u)) >> 16;   // RNE
    return (ushort_t)r;
}
__device__ __forceinline__ unsigned int pk_bf16(float a, float b) {
    __hip_bfloat162 h = __float22bfloat162_rn(make_float2(a, b));
    unsigned int r;
    __builtin_memcpy(&r, &h, 4);
    return r;
}
__device__ __forceinline__ void unpack8(float* dst, uint4 u) {
    dst[0] = __uint_as_float(u.x << 16); dst[1] = __uint_as_float(u.x & 0xffff0000u);
    dst[2] = __uint_as_float(u.y << 16); dst[3] = __uint_as_float(u.y & 0xffff0000u);
    dst[4] = __uint_as_float(u.z << 16); dst[5] = __uint_as_float(u.z & 0xffff0000u);
    dst[6] = __uint_as_float(u.w << 16); dst[7] = __uint_as_float(u.w & 0xffff0000u);
}

// ---------------------------------------------------------------------------
// convert3: fp32 -> bf16 for x, w_qkv, w_out (unchanged)
// ---------------------------------------------------------------------------
#define XN8 (S_LEN * HID / 8)          // 524288
#define QN8 (QKV_O * HID / 8)          // 786432
#define ON8 (HID * HID / 8)            // 524288

__global__ __launch_bounds__(256) void convert3(
    const float* __restrict__ x, const float* __restrict__ wq,
    const float* __restrict__ wo, ushort_t* __restrict__ xb,
    ushort_t* __restrict__ wqb, ushort_t* __restrict__ wob) {
    int i = blockIdx.x * 256 + threadIdx.x;
    const float* s; ushort_t* d; int off;
    if (i < XN8)            { s = x;  d = xb;  off = i; }
    else if (i < XN8 + QN8) { s = wq; d = wqb; off = i - XN8; }
    else                    { s = wo; d = wob; off = i - XN8 - QN8; }
    const float4* sp = (const float4*)s + (size_t)off * 2;
    float4 a = sp[0], b = sp[1];
    *(uint4*)(d + (size_t)off * 8) = make_uint4(
        pk_bf16(a.x, a.y), pk_bf16(a.z, a.w),
        pk_bf16(b.x, b.y), pk_bf16(b.z, b.w));
}

// ---------------------------------------------------------------------------
// gemm_bk64: pure-bf16 GEMM, 64x128 (MxN) tile, BK=64, XOR-swizzled LDS.
// Round-10 gemm64 (BK=32, 64B rows) spent more inner-loop time in LDS reads
// than MFMA: 8-way read aliasing (bank = (row*16+quad*4)%32, rows alternate
// only 2 offsets -> 4.7M conflict cycles) + a barrier-pair per 8 MFMA.
// Here: As[64][64]+Bs[128][64] (24 KB), one barrier-pair per 16 MFMA (m97
// parity), and the XOR swizzle chunk_lds = chunk_glb ^ (row&7) applied in
// the GLOBAL read address (global_load_lds lane->LDS mapping is fixed, so
// the swizzle must live on the source side). Read bank = (chunk*4)%32 with
// chunk = (ks*4+quad)^(l16&7) spanning all 8 groups -> 2-way max (free).
// 4 waves 2x2; each wave 32x64 via 2x4 mfma_16x16x32_bf16 per ks.
// M%64==0, N%128==0, K%64==0.
// ---------------------------------------------------------------------------
template<bool CF32>
__global__ __launch_bounds__(256) void gemm_bk64(
    const ushort_t* __restrict__ A, const ushort_t* __restrict__ Bt,
    void* __restrict__ Cp, int M, int N, int K) {
    __shared__ ushort_t As[64][64];     // 8 KB
    __shared__ ushort_t Bs[128][64];    // 16 KB

    const int t    = threadIdx.x;
    const int wave = t >> 6;
    const int lane = t & 63;
    const int quad = lane >> 4;
    const int l16  = lane & 15;
    const int wm   = (wave >> 1) << 5;   // 0 / 32
    const int wn   = (wave & 1)  << 6;   // 0 / 64
    const int bm   = blockIdx.y * 64;
    const int bn   = blockIdx.x * 128;
    const int lr   = lane >> 3;          // staging row-in-group 0..7
    const int lc   = ((lane & 7) ^ lr) << 3;   // swizzled global chunk*8

    f32x4 acc[2][4];
    #pragma unroll
    for (int i = 0; i < 2; i++)
        #pragma unroll
        for (int j = 0; j < 4; j++) {
            f32x4 z = {0.f, 0.f, 0.f, 0.f};
            acc[i][j] = z;
        }

    const ushort_t* a0 = &A[(size_t)(bm + wave * 16 + lr) * K + lc];
    const ushort_t* b0 = &Bt[(size_t)(bn + wave * 32 + lr) * K + lc];
    const size_t r8 = (size_t)8 * K;

    for (int k0 = 0; k0 < K; k0 += 64) {
        __syncthreads();
        // A tile: 64 rows, 8 rows per issue, 2 issues/wave
        __builtin_amdgcn_global_load_lds(GLB(a0 + k0),          LDSP(&As[wave * 16][0]),      16, 0, 0);
        __builtin_amdgcn_global_load_lds(GLB(a0 + k0 + r8),     LDSP(&As[wave * 16 + 8][0]),  16, 0, 0);
        // B tile: 128 rows, 4 issues/wave
        __builtin_amdgcn_global_load_lds(GLB(b0 + k0),          LDSP(&Bs[wave * 32][0]),      16, 0, 0);
        __builtin_amdgcn_global_load_lds(GLB(b0 + k0 + r8),     LDSP(&Bs[wave * 32 + 8][0]),  16, 0, 0);
        __builtin_amdgcn_global_load_lds(GLB(b0 + k0 + 2 * r8), LDSP(&Bs[wave * 32 + 16][0]), 16, 0, 0);
        __builtin_amdgcn_global_load_lds(GLB(b0 + k0 + 3 * r8), LDSP(&Bs[wave * 32 + 24][0]), 16, 0, 0);
        __syncthreads();

        #pragma unroll
        for (int ks = 0; ks < 2; ks++) {
            // LDS chunk for global chunk g=ks*4+quad at row with row&7==l16&7
            const int ca = (((ks << 2) + quad) ^ (l16 & 7)) << 3;
            bf16x8 af[2], bfr[4];
            #pragma unroll
            for (int i = 0; i < 2; i++)
                af[i] = *(const bf16x8*)&As[wm + i * 16 + l16][ca];
            #pragma unroll
            for (int j = 0; j < 4; j++)
                bfr[j] = *(const bf16x8*)&Bs[wn + j * 16 + l16][ca];

            #pragma unroll
            for (int i = 0; i < 2; i++)
                #pragma unroll
                for (int j = 0; j < 4; j++)
                    acc[i][j] = __builtin_amdgcn_mfma_f32_16x16x32_bf16(
                        af[i], bfr[j], acc[i][j], 0, 0, 0);
        }
    }

    // Epilogue: C/D layout col=lane&15, row=quad*4+reg
    #pragma unroll
    for (int i = 0; i < 2; i++)
        #pragma unroll
        for (int j = 0; j < 4; j++)
            #pragma unroll
            for (int r = 0; r < 4; r++) {
                int row = bm + wm + i * 16 + quad * 4 + r;
                int col = bn + wn + j * 16 + l16;
                if (CF32)
                    ((float*)Cp)[(size_t)row * N + col] = acc[i][j][r];
                else
                    ((ushort_t*)Cp)[(size_t)row * N + col] = f2bf(acc[i][j][r]);
            }
}

// ---------------------------------------------------------------------------
// Fallback GEMM with fused fp32->bf16 staging (small-ws path; unchanged)
// ---------------------------------------------------------------------------
template<bool AF32, bool BF32, bool CF32>
__global__ __launch_bounds__(256) void gemm_bt(
    const void* __restrict__ Ap, const void* __restrict__ Bp,
    void* __restrict__ Cp, int M, int N, int K) {
    __shared__ ushort_t As[128][40];
    __shared__ ushort_t Bs[128][40];

    const int t    = threadIdx.x;
    const int wave = t >> 6;
    const int lane = t & 63;
    const int quad = lane >> 4;
    const int l16  = lane & 15;
    const int wm   = (wave >> 1) << 6;
    const int wn   = (wave & 1)  << 6;
    const int bm   = blockIdx.y * 128;
    const int bn   = blockIdx.x * 128;
    const int sr   = t >> 2;
    const int sc   = (t & 3) << 3;

    f32x4 acc[4][4];
    #pragma unroll
    for (int i = 0; i < 4; i++)
        #pragma unroll
        for (int j = 0; j < 4; j++) {
            f32x4 z = {0.f, 0.f, 0.f, 0.f};
            acc[i][j] = z;
        }

    for (int k0 = 0; k0 < K; k0 += 32) {
        __syncthreads();
        if (AF32) {
            const float* A = (const float*)Ap;
            const float* p0 = &A[(size_t)(bm + sr) * K + k0 + sc];
            const float* p1 = &A[(size_t)(bm + sr + 64) * K + k0 + sc];
            float4 a0 = *(const float4*)p0, a1 = *(const float4*)(p0 + 4);
            float4 b0 = *(const float4*)p1, b1 = *(const float4*)(p1 + 4);
            *(uint4*)&As[sr][sc] = make_uint4(
                pk_bf16(a0.x, a0.y), pk_bf16(a0.z, a0.w),
                pk_bf16(a1.x, a1.y), pk_bf16(a1.z, a1.w));
            *(uint4*)&As[sr + 64][sc] = make_uint4(
                pk_bf16(b0.x, b0.y), pk_bf16(b0.z, b0.w),
                pk_bf16(b1.x, b1.y), pk_bf16(b1.z, b1.w));
        } else {
            const ushort_t* A = (const ushort_t*)Ap;
            *(uint4*)&As[sr][sc]      = *(const uint4*)&A[(size_t)(bm + sr) * K + k0 + sc];
            *(uint4*)&As[sr + 64][sc] = *(const uint4*)&A[(size_t)(bm + sr + 64) * K + k0 + sc];
        }
        if (BF32) {
            const float* B = (const float*)Bp;
            const float* p0 = &B[(size_t)(bn + sr) * K + k0 + sc];
            const float* p1 = &B[(size_t)(bn + sr + 64) * K + k0 + sc];
            float4 a0 = *(const float4*)p0, a1 = *(const float4*)(p0 + 4);
            float4 b0 = *(const float4*)p1, b1 = *(const float4*)(p1 + 4);
            *(uint4*)&Bs[sr][sc] = make_uint4(
                pk_bf16(a0.x, a0.y), pk_bf16(a0.z, a0.w),
                pk_bf16(a1.x, a1.y), pk_bf16(a1.z, a1.w));
            *(uint4*)&Bs[sr + 64][sc] = make_uint4(
                pk_bf16(b0.x, b0.y), pk_bf16(b0.z, b0.w),
                pk_bf16(b1.x, b1.y), pk_bf16(b1.z, b1.w));
        } else {
            const ushort_t* B = (const ushort_t*)Bp;
            *(uint4*)&Bs[sr][sc]      = *(const uint4*)&B[(size_t)(bn + sr) * K + k0 + sc];
            *(uint4*)&Bs[sr + 64][sc] = *(const uint4*)&B[(size_t)(bn + sr + 64) * K + k0 + sc];
        }
        __syncthreads();

        bf16x8 af[4], bfr[4];
        #pragma unroll
        for (int i = 0; i < 4; i++)
            af[i] = *(const bf16x8*)&As[wm + i * 16 + l16][quad * 8];
        #pragma unroll
        for (int j = 0; j < 4; j++)
            bfr[j] = *(const bf16x8*)&Bs[wn + j * 16 + l16][quad * 8];

        #pragma unroll
        for (int i = 0; i < 4; i++)
            #pragma unroll
            for (int j = 0; j < 4; j++)
                acc[i][j] = __builtin_amdgcn_mfma_f32_16x16x32_bf16(
                    af[i], bfr[j], acc[i][j], 0, 0, 0);
    }

    #pragma unroll
    for (int i = 0; i < 4; i++)
        #pragma unroll
        for (int j = 0; j < 4; j++)
            #pragma unroll
            for (int r = 0; r < 4; r++) {
                int row = bm + wm + i * 16 + quad * 4 + r;
                int col = bn + wn + j * 16 + l16;
                if (CF32)
                    ((float*)Cp)[(size_t)row * N + col] = acc[i][j][r];
                else
                    ((ushort_t*)Cp)[(size_t)row * N + col] = f2bf(acc[i][j][r]);
            }
}

// ---------------------------------------------------------------------------
// RoPE in-place (unchanged)
// ---------------------------------------------------------------------------
__global__ __launch_bounds__(256) void rope_kernel(
    ushort_t* __restrict__ qkv, const float* __restrict__ cs,
    const float* __restrict__ sn) {
    int idx = blockIdx.x * 256 + threadIdx.x;
    if (idx >= S_LEN * (NQH + NKVH)) return;
    int s  = idx / (NQH + NKVH);
    int hh = idx - s * (NQH + NKVH);

    ushort_t* p = &qkv[(size_t)s * QKV_O + hh * HD];
    const uint4* p4 = (const uint4*)p;
    float v[HD], c[HD], sv[HD];
    #pragma unroll
    for (int b = 0; b < 8; b++) unpack8(&v[b * 8], p4[b]);
    const float4* c4 = (const float4*)&cs[s * HD];
    const float4* s4 = (const float4*)&sn[s * HD];
    #pragma unroll
    for (int b = 0; b < 16; b++) {
        ((float4*)c)[b]  = c4[b];
        ((float4*)sv)[b] = s4[b];
    }
    float o[HD];
    #pragma unroll
    for (int d = 0; d < 32; d++) {
        o[d]      = v[d] * c[d]           - v[d + 32] * sv[d];
        o[d + 32] = v[d + 32] * c[d + 32] + v[d]      * sv[d + 32];
    }
    unsigned int* pw = (unsigned int*)p;
    #pragma unroll
    for (int d = 0; d < HD; d += 2)
        pw[d >> 1] = pk_bf16(o[d], o[d + 1]);
}

// ---------------------------------------------------------------------------
// attn_v4: complementary-pairing MFMA flash attention (unchanged from round 10)
// ---------------------------------------------------------------------------
__global__ __launch_bounds__(256) void attn_v4(
    const ushort_t* __restrict__ qkv, ushort_t* __restrict__ O) {
    const int bx   = blockIdx.x;            // 512 blocks
    const int h    = bx & 31;               // head
    const int p    = bx >> 5;               // pair index 0..15 (p=0 heaviest)
    const int kvh  = h >> 2;                // GQA group size 4
    const int q0d  = (31 - p) * 64;         // deep Q-tile base row
    const int q0s  = p * 64;                // shallow Q-tile base row
    const int tid  = threadIdx.x;
    const int wave = tid >> 6;
    const int lane = tid & 63;
    const int quad = lane >> 4;
    const int l16  = lane & 15;

    __shared__ __align__(16) ushort_t Ks[64][72];
    __shared__ __align__(16) ushort_t Vt[64][72];
    __shared__ __align__(16) ushort_t Pl[4][32][72];

    const int rowbase0 = q0d + wave * 16;   // mi=0 (deep)
    const int rowbase1 = q0s + wave * 16;   // mi=1 (shallow)

    bf16x8 bq[2][2];
    #pragma unroll
    for (int mi = 0; mi < 2; mi++) {
        const int rb = (mi == 0) ? rowbase0 : rowbase1;
        #pragma unroll
        for (int ks = 0; ks < 2; ks++) {
            uint4 u = *(const uint4*)&qkv[(size_t)(rb + l16) * QKV_O
                                          + h * HD + ks * 32 + quad * 8];
            float f[8]; unpack8(f, u);
            uint4 w = make_uint4(
                pk_bf16(f[0] * 0.125f, f[1] * 0.125f),
                pk_bf16(f[2] * 0.125f, f[3] * 0.125f),
                pk_bf16(f[4] * 0.125f, f[5] * 0.125f),
                pk_bf16(f[6] * 0.125f, f[7] * 0.125f));
            __builtin_memcpy(&bq[mi][ks], &w, 16);
        }
    }

    bf16x8 ones;
    #pragma unroll
    for (int e = 0; e < 8; e++) ones[e] = (__bf16)1.0f;

    f32x4 acc_o[2][4];
    f32x4 acc_l[2];
    #pragma unroll
    for (int mi = 0; mi < 2; mi++) {
        f32x4 z = {0.f, 0.f, 0.f, 0.f};
        acc_l[mi] = z;
        #pragma unroll
        for (int n = 0; n < 4; n++) acc_o[mi][n] = z;
    }

    const int nt = 32 - p;
    const int sr = tid >> 2;
    const int sc = (tid & 3) << 4;

    for (int t = 0; t < nt; t++) {
        const int j0 = t * 64;
        __syncthreads();
        {
            const ushort_t* kp = &qkv[(size_t)(j0 + sr) * QKV_O + K_COL + kvh * HD + sc];
            *(uint4*)&Ks[sr][sc]     = *(const uint4*)kp;
            *(uint4*)&Ks[sr][sc + 8] = *(const uint4*)(kp + 8);
            const ushort_t* vp = &qkv[(size_t)(j0 + sr) * QKV_O + V_COL + kvh * HD + sc];
            ushort_t tmp[16];
            *(uint4*)&tmp[0] = *(const uint4*)vp;
            *(uint4*)&tmp[8] = *(const uint4*)(vp + 8);
            #pragma unroll
            for (int e = 0; e < 16; e++) {
                int d = sc + e;
                Vt[d][(sr + 8 * (d >> 3)) & 63] = tmp[e];
            }
        }
        __syncthreads();

        const bool sact = (t <= p);          // shallow active (block-uniform)

        f32x4 st[2][4];
        #pragma unroll
        for (int mi = 0; mi < 2; mi++)
            #pragma unroll
            for (int nk = 0; nk < 4; nk++) {
                f32x4 z = {0.f, 0.f, 0.f, 0.f};
                st[mi][nk] = z;
            }
        #pragma unroll
        for (int ks = 0; ks < 2; ks++) {
            bf16x8 ak[4];
            #pragma unroll
            for (int nk = 0; nk < 4; nk++)
                ak[nk] = *(const bf16x8*)&Ks[nk * 16 + l16][ks * 32 + quad * 8];
            #pragma unroll
            for (int mi = 0; mi < 2; mi++) {
                if (mi == 1 && !sact) continue;       // uniform, post-unroll
                #pragma unroll
                for (int nk = 0; nk < 4; nk++)
                    st[mi][nk] = __builtin_amdgcn_mfma_f32_16x16x32_bf16(
                        ak[nk], bq[mi][ks], st[mi][nk], 0, 0, 0);
            }
        }

        #pragma unroll
        for (int mi = 0; mi < 2; mi++) {
            if (mi == 1 && !sact) continue;           // uniform, post-unroll
            const bool diag = (mi == 0) ? (t == nt - 1) : (t == p);
            const int qrow = ((mi == 0) ? rowbase0 : rowbase1) + l16;
            #pragma unroll
            for (int nk = 0; nk < 4; nk++) {
                const int kc0 = j0 + nk * 16 + quad * 4;
                float pv[4];
                #pragma unroll
                for (int r = 0; r < 4; r++) {
                    float e = __expf(st[mi][nk][r]);
                    pv[r] = (diag && (kc0 + r > qrow)) ? 0.f : e;
                }
                uint2 w2 = make_uint2(pk_bf16(pv[0], pv[1]), pk_bf16(pv[2], pv[3]));
                *(uint2*)&Pl[wave][mi * 16 + l16][nk * 16 + quad * 4] = w2;
            }
        }

        #pragma unroll
        for (int ksp = 0; ksp < 2; ksp++) {
            bf16x8 bv[4];
            #pragma unroll
            for (int nd = 0; nd < 4; nd++) {
                const int d = nd * 16 + l16;
                bv[nd] = *(const bf16x8*)&Vt[d][(ksp * 32 + quad * 8 + 8 * (d >> 3)) & 63];
            }
            #pragma unroll
            for (int mi = 0; mi < 2; mi++) {
                if (mi == 1 && !sact) continue;       // uniform, post-unroll
                bf16x8 ap = *(const bf16x8*)&Pl[wave][mi * 16 + l16][ksp * 32 + quad * 8];
                acc_l[mi] = __builtin_amdgcn_mfma_f32_16x16x32_bf16(
                    ap, ones, acc_l[mi], 0, 0, 0);
                #pragma unroll
                for (int nd = 0; nd < 4; nd++)
                    acc_o[mi][nd] = __builtin_amdgcn_mfma_f32_16x16x32_bf16(
                        ap, bv[nd], acc_o[mi][nd], 0, 0, 0);
            }
        }
    }

    #pragma unroll
    for (int mi = 0; mi < 2; mi++) {
        const int rb = (mi == 0) ? rowbase0 : rowbase1;
        float inv[4];
        #pragma unroll
        for (int r = 0; r < 4; r++) inv[r] = 1.0f / acc_l[mi][r];
        #pragma unroll
        for (int nd = 0; nd < 4; nd++)
            #pragma unroll
            for (int r = 0; r < 4; r++) {
                int row = rb + quad * 4 + r;
                int col = h * HD + nd * 16 + l16;
                O[(size_t)row * (NQH * HD) + col] = f2bf(acc_o[mi][nd][r] * inv[r]);
            }
    }
}

// ---------------------------------------------------------------------------
extern "C" void kernel_launch(void* const* d_in, const int* in_sizes, int n_in,
                              void* d_out, int out_size, void* d_ws, size_t ws_size,
                              hipStream_t stream) {
    const float* x     = (const float*)d_in[0];  // [2048][2048] fp32
    const float* cosp  = (const float*)d_in[1];  // [2048][64]   fp32
    const float* sinp  = (const float*)d_in[2];  // [2048][64]   fp32
    const float* w_qkv = (const float*)d_in[3];  // [3072][2048] fp32
    const float* w_out = (const float*)d_in[4];  // [2048][2048] fp32
    float* out = (float*)d_out;                  // [2048][2048] fp32

    const size_t NQKV = (size_t)S_LEN * QKV_O;   // 6291456
    const size_t NH2  = (size_t)S_LEN * HID;     // 4194304
    const size_t need = 2 * (NQKV + NH2) * sizeof(ushort_t);  // 41.9 MB

    ushort_t* qkv = (ushort_t*)d_ws;             // bf16 [2048][3072]

    if (ws_size >= need) {
        ushort_t* x_bf    = qkv + NQKV;
        ushort_t* attnO   = x_bf;                // disjoint lifetimes
        ushort_t* wqkv_bf = x_bf + NH2;
        ushort_t* wout_bf = wqkv_bf + NQKV;

        convert3<<<XN8 / 256 + QN8 / 256 + ON8 / 256, 256, 0, stream>>>(
            x, w_qkv, w_out, x_bf, wqkv_bf, wout_bf);

        // 1) qkv = x @ w_qkv^T — 64x128 tiles, BK=64: 24x32 = 768 blocks
        dim3 g1(QKV_O / 128, S_LEN / 64);
        gemm_bk64<false><<<g1, 256, 0, stream>>>(x_bf, wqkv_bf, qkv, S_LEN, QKV_O, HID);

        int rope_threads = S_LEN * (NQH + NKVH);
        rope_kernel<<<(rope_threads + 255) / 256, 256, 0, stream>>>(qkv, cosp, sinp);

        attn_v4<<<16 * NQH, 256, 0, stream>>>(qkv, attnO);

        // 4) out = attnO @ w_out^T — 16x32 = 512 blocks
        dim3 g2(HID / 128, S_LEN / 64);
        gemm_bk64<true><<<g2, 256, 0, stream>>>(attnO, wout_bf, out, S_LEN, HID, HID);
    } else {
        ushort_t* attnO = qkv + NQKV;

        dim3 g1(QKV_O / 128, S_LEN / 128);
        gemm_bt<true, true, false><<<g1, 256, 0, stream>>>(x, w_qkv, qkv, S_LEN, QKV_O, HID);

        int rope_threads = S_LEN * (NQH + NKVH);
        rope_kernel<<<(rope_threads + 255) / 256, 256, 0, stream>>>(qkv, cosp, sinp);

        attn_v4<<<16 * NQH, 256, 0, stream>>>(qkv, attnO);

        dim3 g2(HID / 128, S_LEN / 128);
        gemm_bt<false, true, true><<<g2, 256, 0, stream>>>(attnO, w_out, out, S_LEN, HID, HID);
    }
}

// Round 12
// 216.536 us; speedup vs baseline: 2.2928x; 1.0046x over previous
//
#include <hip/hip_runtime.h>
#include <hip/hip_bf16.h>
#include <stdint.h>

// Problem constants (B=1). I/O dtype: fp32. Internals bf16 (MFMA path).
#define S_LEN 2048
#define HID   2048
#define NQH   32
#define NKVH  8
#define HD    64
#define QKV_O 3072      // (32 + 2*8) * 64
#define K_COL 2048      // col offset of K block in qkv row
#define V_COL 2560      // col offset of V block in qkv row

typedef unsigned short ushort_t;
typedef __bf16 bf16x8 __attribute__((ext_vector_type(8)));
typedef float  f32x4  __attribute__((ext_vector_type(4)));

#define GLB(p) ((const __attribute__((address_space(1))) void*)(p))
#define LDSP(p) ((__attribute__((address_space(3))) void*)(p))

__device__ __forceinline__ ushort_t f2bf(float f) {
    unsigned int x = __float_as_uint(f);
    unsigned int r = (x + 0x7fffu + ((x >> 16) & 1u)) >> 16;   // RNE
    return (ushort_t)r;
}
__device__ __forceinline__ unsigned int pk_bf16(float a, float b) {
    __hip_bfloat162 h = __float22bfloat162_rn(make_float2(a, b));
    unsigned int r;
    __builtin_memcpy(&r, &h, 4);
    return r;
}
__device__ __forceinline__ void unpack8(float* dst, uint4 u) {
    dst[0] = __uint_as_float(u.x << 16); dst[1] = __uint_as_float(u.x & 0xffff0000u);
    dst[2] = __uint_as_float(u.y << 16); dst[3] = __uint_as_float(u.y & 0xffff0000u);
    dst[4] = __uint_as_float(u.z << 16); dst[5] = __uint_as_float(u.z & 0xffff0000u);
    dst[6] = __uint_as_float(u.w << 16); dst[7] = __uint_as_float(u.w & 0xffff0000u);
}

// ---------------------------------------------------------------------------
// convert3: fp32 -> bf16 for x, w_qkv, w_out (unchanged)
// ---------------------------------------------------------------------------
#define XN8 (S_LEN * HID / 8)          // 524288
#define QN8 (QKV_O * HID / 8)          // 786432
#define ON8 (HID * HID / 8)            // 524288

__global__ __launch_bounds__(256) void convert3(
    const float* __restrict__ x, const float* __restrict__ wq,
    const float* __restrict__ wo, ushort_t* __restrict__ xb,
    ushort_t* __restrict__ wqb, ushort_t* __restrict__ wob) {
    int i = blockIdx.x * 256 + threadIdx.x;
    const float* s; ushort_t* d; int off;
    if (i < XN8)            { s = x;  d = xb;  off = i; }
    else if (i < XN8 + QN8) { s = wq; d = wqb; off = i - XN8; }
    else                    { s = wo; d = wob; off = i - XN8 - QN8; }
    const float4* sp = (const float4*)s + (size_t)off * 2;
    float4 a = sp[0], b = sp[1];
    *(uint4*)(d + (size_t)off * 8) = make_uint4(
        pk_bf16(a.x, a.y), pk_bf16(a.z, a.w),
        pk_bf16(b.x, b.y), pk_bf16(b.z, b.w));
}

// ---------------------------------------------------------------------------
// gemm_bk64: pure-bf16 GEMM, 64x128 tile, BK=64, XOR-swizzled LDS
// (unchanged from round 11 — dropped out of top-5)
// ---------------------------------------------------------------------------
template<bool CF32>
__global__ __launch_bounds__(256) void gemm_bk64(
    const ushort_t* __restrict__ A, const ushort_t* __restrict__ Bt,
    void* __restrict__ Cp, int M, int N, int K) {
    __shared__ ushort_t As[64][64];     // 8 KB
    __shared__ ushort_t Bs[128][64];    // 16 KB

    const int t    = threadIdx.x;
    const int wave = t >> 6;
    const int lane = t & 63;
    const int quad = lane >> 4;
    const int l16  = lane & 15;
    const int wm   = (wave >> 1) << 5;
    const int wn   = (wave & 1)  << 6;
    const int bm   = blockIdx.y * 64;
    const int bn   = blockIdx.x * 128;
    const int lr   = lane >> 3;
    const int lc   = ((lane & 7) ^ lr) << 3;

    f32x4 acc[2][4];
    #pragma unroll
    for (int i = 0; i < 2; i++)
        #pragma unroll
        for (int j = 0; j < 4; j++) {
            f32x4 z = {0.f, 0.f, 0.f, 0.f};
            acc[i][j] = z;
        }

    const ushort_t* a0 = &A[(size_t)(bm + wave * 16 + lr) * K + lc];
    const ushort_t* b0 = &Bt[(size_t)(bn + wave * 32 + lr) * K + lc];
    const size_t r8 = (size_t)8 * K;

    for (int k0 = 0; k0 < K; k0 += 64) {
        __syncthreads();
        __builtin_amdgcn_global_load_lds(GLB(a0 + k0),          LDSP(&As[wave * 16][0]),      16, 0, 0);
        __builtin_amdgcn_global_load_lds(GLB(a0 + k0 + r8),     LDSP(&As[wave * 16 + 8][0]),  16, 0, 0);
        __builtin_amdgcn_global_load_lds(GLB(b0 + k0),          LDSP(&Bs[wave * 32][0]),      16, 0, 0);
        __builtin_amdgcn_global_load_lds(GLB(b0 + k0 + r8),     LDSP(&Bs[wave * 32 + 8][0]),  16, 0, 0);
        __builtin_amdgcn_global_load_lds(GLB(b0 + k0 + 2 * r8), LDSP(&Bs[wave * 32 + 16][0]), 16, 0, 0);
        __builtin_amdgcn_global_load_lds(GLB(b0 + k0 + 3 * r8), LDSP(&Bs[wave * 32 + 24][0]), 16, 0, 0);
        __syncthreads();

        #pragma unroll
        for (int ks = 0; ks < 2; ks++) {
            const int ca = (((ks << 2) + quad) ^ (l16 & 7)) << 3;
            bf16x8 af[2], bfr[4];
            #pragma unroll
            for (int i = 0; i < 2; i++)
                af[i] = *(const bf16x8*)&As[wm + i * 16 + l16][ca];
            #pragma unroll
            for (int j = 0; j < 4; j++)
                bfr[j] = *(const bf16x8*)&Bs[wn + j * 16 + l16][ca];

            #pragma unroll
            for (int i = 0; i < 2; i++)
                #pragma unroll
                for (int j = 0; j < 4; j++)
                    acc[i][j] = __builtin_amdgcn_mfma_f32_16x16x32_bf16(
                        af[i], bfr[j], acc[i][j], 0, 0, 0);
        }
    }

    #pragma unroll
    for (int i = 0; i < 2; i++)
        #pragma unroll
        for (int j = 0; j < 4; j++)
            #pragma unroll
            for (int r = 0; r < 4; r++) {
                int row = bm + wm + i * 16 + quad * 4 + r;
                int col = bn + wn + j * 16 + l16;
                if (CF32)
                    ((float*)Cp)[(size_t)row * N + col] = acc[i][j][r];
                else
                    ((ushort_t*)Cp)[(size_t)row * N + col] = f2bf(acc[i][j][r]);
            }
}

// ---------------------------------------------------------------------------
// Fallback GEMM with fused fp32->bf16 staging (small-ws path; unchanged)
// ---------------------------------------------------------------------------
template<bool AF32, bool BF32, bool CF32>
__global__ __launch_bounds__(256) void gemm_bt(
    const void* __restrict__ Ap, const void* __restrict__ Bp,
    void* __restrict__ Cp, int M, int N, int K) {
    __shared__ ushort_t As[128][40];
    __shared__ ushort_t Bs[128][40];

    const int t    = threadIdx.x;
    const int wave = t >> 6;
    const int lane = t & 63;
    const int quad = lane >> 4;
    const int l16  = lane & 15;
    const int wm   = (wave >> 1) << 6;
    const int wn   = (wave & 1)  << 6;
    const int bm   = blockIdx.y * 128;
    const int bn   = blockIdx.x * 128;
    const int sr   = t >> 2;
    const int sc   = (t & 3) << 3;

    f32x4 acc[4][4];
    #pragma unroll
    for (int i = 0; i < 4; i++)
        #pragma unroll
        for (int j = 0; j < 4; j++) {
            f32x4 z = {0.f, 0.f, 0.f, 0.f};
            acc[i][j] = z;
        }

    for (int k0 = 0; k0 < K; k0 += 32) {
        __syncthreads();
        if (AF32) {
            const float* A = (const float*)Ap;
            const float* p0 = &A[(size_t)(bm + sr) * K + k0 + sc];
            const float* p1 = &A[(size_t)(bm + sr + 64) * K + k0 + sc];
            float4 a0 = *(const float4*)p0, a1 = *(const float4*)(p0 + 4);
            float4 b0 = *(const float4*)p1, b1 = *(const float4*)(p1 + 4);
            *(uint4*)&As[sr][sc] = make_uint4(
                pk_bf16(a0.x, a0.y), pk_bf16(a0.z, a0.w),
                pk_bf16(a1.x, a1.y), pk_bf16(a1.z, a1.w));
            *(uint4*)&As[sr + 64][sc] = make_uint4(
                pk_bf16(b0.x, b0.y), pk_bf16(b0.z, b0.w),
                pk_bf16(b1.x, b1.y), pk_bf16(b1.z, b1.w));
        } else {
            const ushort_t* A = (const ushort_t*)Ap;
            *(uint4*)&As[sr][sc]      = *(const uint4*)&A[(size_t)(bm + sr) * K + k0 + sc];
            *(uint4*)&As[sr + 64][sc] = *(const uint4*)&A[(size_t)(bm + sr + 64) * K + k0 + sc];
        }
        if (BF32) {
            const float* B = (const float*)Bp;
            const float* p0 = &B[(size_t)(bn + sr) * K + k0 + sc];
            const float* p1 = &B[(size_t)(bn + sr + 64) * K + k0 + sc];
            float4 a0 = *(const float4*)p0, a1 = *(const float4*)(p0 + 4);
            float4 b0 = *(const float4*)p1, b1 = *(const float4*)(p1 + 4);
            *(uint4*)&Bs[sr][sc] = make_uint4(
                pk_bf16(a0.x, a0.y), pk_bf16(a0.z, a0.w),
                pk_bf16(a1.x, a1.y), pk_bf16(a1.z, a1.w));
            *(uint4*)&Bs[sr + 64][sc] = make_uint4(
                pk_bf16(b0.x, b0.y), pk_bf16(b0.z, b0.w),
                pk_bf16(b1.x, b1.y), pk_bf16(b1.z, b1.w));
        } else {
            const ushort_t* B = (const ushort_t*)Bp;
            *(uint4*)&Bs[sr][sc]      = *(const uint4*)&B[(size_t)(bn + sr) * K + k0 + sc];
            *(uint4*)&Bs[sr + 64][sc] = *(const uint4*)&B[(size_t)(bn + sr + 64) * K + k0 + sc];
        }
        __syncthreads();

        bf16x8 af[4], bfr[4];
        #pragma unroll
        for (int i = 0; i < 4; i++)
            af[i] = *(const bf16x8*)&As[wm + i * 16 + l16][quad * 8];
        #pragma unroll
        for (int j = 0; j < 4; j++)
            bfr[j] = *(const bf16x8*)&Bs[wn + j * 16 + l16][quad * 8];

        #pragma unroll
        for (int i = 0; i < 4; i++)
            #pragma unroll
            for (int j = 0; j < 4; j++)
                acc[i][j] = __builtin_amdgcn_mfma_f32_16x16x32_bf16(
                    af[i], bfr[j], acc[i][j], 0, 0, 0);
    }

    #pragma unroll
    for (int i = 0; i < 4; i++)
        #pragma unroll
        for (int j = 0; j < 4; j++)
            #pragma unroll
            for (int r = 0; r < 4; r++) {
                int row = bm + wm + i * 16 + quad * 4 + r;
                int col = bn + wn + j * 16 + l16;
                if (CF32)
                    ((float*)Cp)[(size_t)row * N + col] = acc[i][j][r];
                else
                    ((ushort_t*)Cp)[(size_t)row * N + col] = f2bf(acc[i][j][r]);
            }
}

// ---------------------------------------------------------------------------
// RoPE in-place (unchanged)
// ---------------------------------------------------------------------------
__global__ __launch_bounds__(256) void rope_kernel(
    ushort_t* __restrict__ qkv, const float* __restrict__ cs,
    const float* __restrict__ sn) {
    int idx = blockIdx.x * 256 + threadIdx.x;
    if (idx >= S_LEN * (NQH + NKVH)) return;
    int s  = idx / (NQH + NKVH);
    int hh = idx - s * (NQH + NKVH);

    ushort_t* p = &qkv[(size_t)s * QKV_O + hh * HD];
    const uint4* p4 = (const uint4*)p;
    float v[HD], c[HD], sv[HD];
    #pragma unroll
    for (int b = 0; b < 8; b++) unpack8(&v[b * 8], p4[b]);
    const float4* c4 = (const float4*)&cs[s * HD];
    const float4* s4 = (const float4*)&sn[s * HD];
    #pragma unroll
    for (int b = 0; b < 16; b++) {
        ((float4*)c)[b]  = c4[b];
        ((float4*)sv)[b] = s4[b];
    }
    float o[HD];
    #pragma unroll
    for (int d = 0; d < 32; d++) {
        o[d]      = v[d] * c[d]           - v[d + 32] * sv[d];
        o[d + 32] = v[d + 32] * c[d + 32] + v[d]      * sv[d + 32];
    }
    unsigned int* pw = (unsigned int*)p;
    #pragma unroll
    for (int d = 0; d < HD; d += 2)
        pw[d >> 1] = pk_bf16(o[d], o[d + 1]);
}

// ---------------------------------------------------------------------------
// attn_v5: attn_v4 (complementary pairing, S^T orientation) + DOUBLE-BUFFERED
// K/V staging. Round-11 counters (MfmaUtil 15%, VALU 41%, 2 barrier drains
// per tile with staging global-load latency inside the critical path) say the
// kernel is serial-chain-bound. Here: tile t+1's global reads issue into
// VGPRs BEFORE tile t's compute (loads fly during MFMA+exp), LDS writes go
// to the alternate buffer after compute, ONE barrier per tile. Pl stays
// single-buffered (same-wave write->read only). LDS 36.9->55.3 KB = still
// 2 blocks/CU, which equals the 512-block grid's residency -> free.
// ---------------------------------------------------------------------------
__global__ __launch_bounds__(256) void attn_v5(
    const ushort_t* __restrict__ qkv, ushort_t* __restrict__ O) {
    const int bx   = blockIdx.x;            // 512 blocks
    const int h    = bx & 31;               // head
    const int p    = bx >> 5;               // pair index 0..15 (p=0 heaviest)
    const int kvh  = h >> 2;                // GQA group size 4
    const int q0d  = (31 - p) * 64;         // deep Q-tile base row
    const int q0s  = p * 64;                // shallow Q-tile base row
    const int tid  = threadIdx.x;
    const int wave = tid >> 6;
    const int lane = tid & 63;
    const int quad = lane >> 4;
    const int l16  = lane & 15;

    __shared__ __align__(16) ushort_t Ks[2][64][72];   // 18.4 KB (dbuf)
    __shared__ __align__(16) ushort_t Vt[2][64][72];   // 18.4 KB (dbuf)
    __shared__ __align__(16) ushort_t Pl[4][32][72];   // 18.4 KB

    const int rowbase0 = q0d + wave * 16;   // mi=0 (deep)
    const int rowbase1 = q0s + wave * 16;   // mi=1 (shallow)

    // Q B-frags (lane l16 = qrow), pre-scaled by 1/8 (exact in bf16)
    bf16x8 bq[2][2];
    #pragma unroll
    for (int mi = 0; mi < 2; mi++) {
        const int rb = (mi == 0) ? rowbase0 : rowbase1;
        #pragma unroll
        for (int ks = 0; ks < 2; ks++) {
            uint4 u = *(const uint4*)&qkv[(size_t)(rb + l16) * QKV_O
                                          + h * HD + ks * 32 + quad * 8];
            float f[8]; unpack8(f, u);
            uint4 w = make_uint4(
                pk_bf16(f[0] * 0.125f, f[1] * 0.125f),
                pk_bf16(f[2] * 0.125f, f[3] * 0.125f),
                pk_bf16(f[4] * 0.125f, f[5] * 0.125f),
                pk_bf16(f[6] * 0.125f, f[7] * 0.125f));
            __builtin_memcpy(&bq[mi][ks], &w, 16);
        }
    }

    bf16x8 ones;
    #pragma unroll
    for (int e = 0; e < 8; e++) ones[e] = (__bf16)1.0f;

    f32x4 acc_o[2][4];
    f32x4 acc_l[2];
    #pragma unroll
    for (int mi = 0; mi < 2; mi++) {
        f32x4 z = {0.f, 0.f, 0.f, 0.f};
        acc_l[mi] = z;
        #pragma unroll
        for (int n = 0; n < 4; n++) acc_o[mi][n] = z;
    }

    const int nt = 32 - p;               // K tiles for the deep tile
    const int sr = tid >> 2;             // staging kcol 0..63
    const int sc = (tid & 3) << 4;       // staging d {0,16,32,48}

    // ---- prologue: stage tile 0 into buffer 0 ----
    {
        const ushort_t* kp = &qkv[(size_t)sr * QKV_O + K_COL + kvh * HD + sc];
        *(uint4*)&Ks[0][sr][sc]     = *(const uint4*)kp;
        *(uint4*)&Ks[0][sr][sc + 8] = *(const uint4*)(kp + 8);
        const ushort_t* vp = &qkv[(size_t)sr * QKV_O + V_COL + kvh * HD + sc];
        ushort_t tmp[16];
        *(uint4*)&tmp[0] = *(const uint4*)vp;
        *(uint4*)&tmp[8] = *(const uint4*)(vp + 8);
        #pragma unroll
        for (int e = 0; e < 16; e++) {
            int d = sc + e;
            Vt[0][d][(sr + 8 * (d >> 3)) & 63] = tmp[e];
        }
    }
    __syncthreads();

    for (int t = 0; t < nt; t++) {
        const int cur = t & 1, nxt = cur ^ 1;
        const int j0 = t * 64;
        const bool hasNext = (t + 1 < nt);   // block-uniform

        // ---- prefetch tile t+1 globals into VGPRs (in flight during compute) ----
        uint4 ka, kb, va, vb;
        if (hasNext) {
            const size_t rbase = (size_t)(j0 + 64 + sr) * QKV_O;
            const ushort_t* kp = &qkv[rbase + K_COL + kvh * HD + sc];
            ka = *(const uint4*)kp; kb = *(const uint4*)(kp + 8);
            const ushort_t* vp = &qkv[rbase + V_COL + kvh * HD + sc];
            va = *(const uint4*)vp; vb = *(const uint4*)(vp + 8);
        }

        const bool sact = (t <= p);          // shallow active (block-uniform)

        // ---- S^T = K·Q^T ----
        f32x4 st[2][4];
        #pragma unroll
        for (int mi = 0; mi < 2; mi++)
            #pragma unroll
            for (int nk = 0; nk < 4; nk++) {
                f32x4 z = {0.f, 0.f, 0.f, 0.f};
                st[mi][nk] = z;
            }
        #pragma unroll
        for (int ks = 0; ks < 2; ks++) {
            bf16x8 ak[4];
            #pragma unroll
            for (int nk = 0; nk < 4; nk++)
                ak[nk] = *(const bf16x8*)&Ks[cur][nk * 16 + l16][ks * 32 + quad * 8];
            #pragma unroll
            for (int mi = 0; mi < 2; mi++) {
                if (mi == 1 && !sact) continue;       // uniform, post-unroll
                #pragma unroll
                for (int nk = 0; nk < 4; nk++)
                    st[mi][nk] = __builtin_amdgcn_mfma_f32_16x16x32_bf16(
                        ak[nk], bq[mi][ks], st[mi][nk], 0, 0, 0);
            }
        }

        // ---- exp + causal mask, b64 P stores ----
        #pragma unroll
        for (int mi = 0; mi < 2; mi++) {
            if (mi == 1 && !sact) continue;           // uniform, post-unroll
            const bool diag = (mi == 0) ? (t == nt - 1) : (t == p);
            const int qrow = ((mi == 0) ? rowbase0 : rowbase1) + l16;
            #pragma unroll
            for (int nk = 0; nk < 4; nk++) {
                const int kc0 = j0 + nk * 16 + quad * 4;
                float pv[4];
                #pragma unroll
                for (int r = 0; r < 4; r++) {
                    float e = __expf(st[mi][nk][r]);
                    pv[r] = (diag && (kc0 + r > qrow)) ? 0.f : e;
                }
                uint2 w2 = make_uint2(pk_bf16(pv[0], pv[1]), pk_bf16(pv[2], pv[3]));
                *(uint2*)&Pl[wave][mi * 16 + l16][nk * 16 + quad * 4] = w2;
            }
        }

        // ---- l += P·1 ; O += P·V ----
        #pragma unroll
        for (int ksp = 0; ksp < 2; ksp++) {
            bf16x8 bv[4];
            #pragma unroll
            for (int nd = 0; nd < 4; nd++) {
                const int d = nd * 16 + l16;
                bv[nd] = *(const bf16x8*)&Vt[cur][d][(ksp * 32 + quad * 8 + 8 * (d >> 3)) & 63];
            }
            #pragma unroll
            for (int mi = 0; mi < 2; mi++) {
                if (mi == 1 && !sact) continue;       // uniform, post-unroll
                bf16x8 ap = *(const bf16x8*)&Pl[wave][mi * 16 + l16][ksp * 32 + quad * 8];
                acc_l[mi] = __builtin_amdgcn_mfma_f32_16x16x32_bf16(
                    ap, ones, acc_l[mi], 0, 0, 0);
                #pragma unroll
                for (int nd = 0; nd < 4; nd++)
                    acc_o[mi][nd] = __builtin_amdgcn_mfma_f32_16x16x32_bf16(
                        ap, bv[nd], acc_o[mi][nd], 0, 0, 0);
            }
        }

        // ---- publish prefetched tile t+1 into the alternate buffer ----
        if (hasNext) {
            *(uint4*)&Ks[nxt][sr][sc]     = ka;
            *(uint4*)&Ks[nxt][sr][sc + 8] = kb;
            ushort_t tmp[16];
            *(uint4*)&tmp[0] = va;
            *(uint4*)&tmp[8] = vb;
            #pragma unroll
            for (int e = 0; e < 16; e++) {
                int d = sc + e;
                Vt[nxt][d][(sr + 8 * (d >> 3)) & 63] = tmp[e];
            }
        }
        __syncthreads();   // ONE barrier per tile (publishes nxt, retires cur)
    }

    // ---- epilogue: O / l  (C-layout: local qrow=quad*4+r, d=nd*16+l16) ----
    #pragma unroll
    for (int mi = 0; mi < 2; mi++) {
        const int rb = (mi == 0) ? rowbase0 : rowbase1;
        float inv[4];
        #pragma unroll
        for (int r = 0; r < 4; r++) inv[r] = 1.0f / acc_l[mi][r];
        #pragma unroll
        for (int nd = 0; nd < 4; nd++)
            #pragma unroll
            for (int r = 0; r < 4; r++) {
                int row = rb + quad * 4 + r;
                int col = h * HD + nd * 16 + l16;
                O[(size_t)row * (NQH * HD) + col] = f2bf(acc_o[mi][nd][r] * inv[r]);
            }
    }
}

// ---------------------------------------------------------------------------
extern "C" void kernel_launch(void* const* d_in, const int* in_sizes, int n_in,
                              void* d_out, int out_size, void* d_ws, size_t ws_size,
                              hipStream_t stream) {
    const float* x     = (const float*)d_in[0];  // [2048][2048] fp32
    const float* cosp  = (const float*)d_in[1];  // [2048][64]   fp32
    const float* sinp  = (const float*)d_in[2];  // [2048][64]   fp32
    const float* w_qkv = (const float*)d_in[3];  // [3072][2048] fp32
    const float* w_out = (const float*)d_in[4];  // [2048][2048] fp32
    float* out = (float*)d_out;                  // [2048][2048] fp32

    const size_t NQKV = (size_t)S_LEN * QKV_O;   // 6291456
    const size_t NH2  = (size_t)S_LEN * HID;     // 4194304
    const size_t need = 2 * (NQKV + NH2) * sizeof(ushort_t);  // 41.9 MB

    ushort_t* qkv = (ushort_t*)d_ws;             // bf16 [2048][3072]

    if (ws_size >= need) {
        ushort_t* x_bf    = qkv + NQKV;
        ushort_t* attnO   = x_bf;                // disjoint lifetimes
        ushort_t* wqkv_bf = x_bf + NH2;
        ushort_t* wout_bf = wqkv_bf + NQKV;

        convert3<<<XN8 / 256 + QN8 / 256 + ON8 / 256, 256, 0, stream>>>(
            x, w_qkv, w_out, x_bf, wqkv_bf, wout_bf);

        dim3 g1(QKV_O / 128, S_LEN / 64);
        gemm_bk64<false><<<g1, 256, 0, stream>>>(x_bf, wqkv_bf, qkv, S_LEN, QKV_O, HID);

        int rope_threads = S_LEN * (NQH + NKVH);
        rope_kernel<<<(rope_threads + 255) / 256, 256, 0, stream>>>(qkv, cosp, sinp);

        attn_v5<<<16 * NQH, 256, 0, stream>>>(qkv, attnO);

        dim3 g2(HID / 128, S_LEN / 64);
        gemm_bk64<true><<<g2, 256, 0, stream>>>(attnO, wout_bf, out, S_LEN, HID, HID);
    } else {
        ushort_t* attnO = qkv + NQKV;

        dim3 g1(QKV_O / 128, S_LEN / 128);
        gemm_bt<true, true, false><<<g1, 256, 0, stream>>>(x, w_qkv, qkv, S_LEN, QKV_O, HID);

        int rope_threads = S_LEN * (NQH + NKVH);
        rope_kernel<<<(rope_threads + 255) / 256, 256, 0, stream>>>(qkv, cosp, sinp);

        attn_v5<<<16 * NQH, 256, 0, stream>>>(qkv, attnO);

        dim3 g2(HID / 128, S_LEN / 128);
        gemm_bt<false, true, true><<<g2, 256, 0, stream>>>(attnO, w_out, out, S_LEN, HID, HID);
    }
}

// Round 13
// 210.107 us; speedup vs baseline: 2.3629x; 1.0306x over previous
//
#include <hip/hip_runtime.h>
#include <hip/hip_bf16.h>
#include <stdint.h>

// Problem constants (B=1). I/O dtype: fp32. Internals bf16 (MFMA path).
#define S_LEN 2048
#define HID   2048
#define NQH   32
#define NKVH  8
#define HD    64
#define QKV_O 3072      // (32 + 2*8) * 64
#define K_COL 2048      // col offset of K block in qkv row
#define V_COL 2560      // col offset of V block in qkv row

typedef unsigned short ushort_t;
typedef __bf16 bf16x8 __attribute__((ext_vector_type(8)));
typedef float  f32x4  __attribute__((ext_vector_type(4)));

#define GLB(p) ((const __attribute__((address_space(1))) void*)(p))
#define LDSP(p) ((__attribute__((address_space(3))) void*)(p))

__device__ __forceinline__ ushort_t f2bf(float f) {
    unsigned int x = __float_as_uint(f);
    unsigned int r = (x + 0x7fffu + ((x >> 16) & 1u)) >> 16;   // RNE
    return (ushort_t)r;
}
__device__ __forceinline__ unsigned int pk_bf16(float a, float b) {
    __hip_bfloat162 h = __float22bfloat162_rn(make_float2(a, b));
    unsigned int r;
    __builtin_memcpy(&r, &h, 4);
    return r;
}
__device__ __forceinline__ void unpack8(float* dst, uint4 u) {
    dst[0] = __uint_as_float(u.x << 16); dst[1] = __uint_as_float(u.x & 0xffff0000u);
    dst[2] = __uint_as_float(u.y << 16); dst[3] = __uint_as_float(u.y & 0xffff0000u);
    dst[4] = __uint_as_float(u.z << 16); dst[5] = __uint_as_float(u.z & 0xffff0000u);
    dst[6] = __uint_as_float(u.w << 16); dst[7] = __uint_as_float(u.w & 0xffff0000u);
}

// ---------------------------------------------------------------------------
// convert3: fp32 -> bf16 for x, w_qkv, w_out (unchanged)
// ---------------------------------------------------------------------------
#define XN8 (S_LEN * HID / 8)          // 524288
#define QN8 (QKV_O * HID / 8)          // 786432
#define ON8 (HID * HID / 8)            // 524288

__global__ __launch_bounds__(256) void convert3(
    const float* __restrict__ x, const float* __restrict__ wq,
    const float* __restrict__ wo, ushort_t* __restrict__ xb,
    ushort_t* __restrict__ wqb, ushort_t* __restrict__ wob) {
    int i = blockIdx.x * 256 + threadIdx.x;
    const float* s; ushort_t* d; int off;
    if (i < XN8)            { s = x;  d = xb;  off = i; }
    else if (i < XN8 + QN8) { s = wq; d = wqb; off = i - XN8; }
    else                    { s = wo; d = wob; off = i - XN8 - QN8; }
    const float4* sp = (const float4*)s + (size_t)off * 2;
    float4 a = sp[0], b = sp[1];
    *(uint4*)(d + (size_t)off * 8) = make_uint4(
        pk_bf16(a.x, a.y), pk_bf16(a.z, a.w),
        pk_bf16(b.x, b.y), pk_bf16(b.z, b.w));
}

// ---------------------------------------------------------------------------
// gemm_bk64: pure-bf16 GEMM, 64x128 tile, BK=64, XOR-swizzled LDS
// (round-11 structure) + OPTIONAL FUSED ROPE EPILOGUE (ROPE template arg).
// RoPE fuses in-lane: each wave owns one 64-col head slice; lane reg nd holds
// head-dim d=nd*16+l16, and the rotate-half partner d+-32 is reg nd+-2 of the
// SAME lane. Applied (block-uniform) when bn < V_COL (tile entirely q or k;
// head=64 divides tile=128). Rope runs on fp32 acc before the bf16 store —
// one fewer rounding than the separate rope_kernel pass it replaces.
// ---------------------------------------------------------------------------
template<bool CF32, bool ROPE>
__global__ __launch_bounds__(256) void gemm_bk64(
    const ushort_t* __restrict__ A, const ushort_t* __restrict__ Bt,
    void* __restrict__ Cp, int M, int N, int K,
    const float* __restrict__ cs, const float* __restrict__ sn) {
    __shared__ ushort_t As[64][64];     // 8 KB
    __shared__ ushort_t Bs[128][64];    // 16 KB

    const int t    = threadIdx.x;
    const int wave = t >> 6;
    const int lane = t & 63;
    const int quad = lane >> 4;
    const int l16  = lane & 15;
    const int wm   = (wave >> 1) << 5;
    const int wn   = (wave & 1)  << 6;
    const int bm   = blockIdx.y * 64;
    const int bn   = blockIdx.x * 128;
    const int lr   = lane >> 3;
    const int lc   = ((lane & 7) ^ lr) << 3;

    f32x4 acc[2][4];
    #pragma unroll
    for (int i = 0; i < 2; i++)
        #pragma unroll
        for (int j = 0; j < 4; j++) {
            f32x4 z = {0.f, 0.f, 0.f, 0.f};
            acc[i][j] = z;
        }

    const ushort_t* a0 = &A[(size_t)(bm + wave * 16 + lr) * K + lc];
    const ushort_t* b0 = &Bt[(size_t)(bn + wave * 32 + lr) * K + lc];
    const size_t r8 = (size_t)8 * K;

    for (int k0 = 0; k0 < K; k0 += 64) {
        __syncthreads();
        __builtin_amdgcn_global_load_lds(GLB(a0 + k0),          LDSP(&As[wave * 16][0]),      16, 0, 0);
        __builtin_amdgcn_global_load_lds(GLB(a0 + k0 + r8),     LDSP(&As[wave * 16 + 8][0]),  16, 0, 0);
        __builtin_amdgcn_global_load_lds(GLB(b0 + k0),          LDSP(&Bs[wave * 32][0]),      16, 0, 0);
        __builtin_amdgcn_global_load_lds(GLB(b0 + k0 + r8),     LDSP(&Bs[wave * 32 + 8][0]),  16, 0, 0);
        __builtin_amdgcn_global_load_lds(GLB(b0 + k0 + 2 * r8), LDSP(&Bs[wave * 32 + 16][0]), 16, 0, 0);
        __builtin_amdgcn_global_load_lds(GLB(b0 + k0 + 3 * r8), LDSP(&Bs[wave * 32 + 24][0]), 16, 0, 0);
        __syncthreads();

        #pragma unroll
        for (int ks = 0; ks < 2; ks++) {
            const int ca = (((ks << 2) + quad) ^ (l16 & 7)) << 3;
            bf16x8 af[2], bfr[4];
            #pragma unroll
            for (int i = 0; i < 2; i++)
                af[i] = *(const bf16x8*)&As[wm + i * 16 + l16][ca];
            #pragma unroll
            for (int j = 0; j < 4; j++)
                bfr[j] = *(const bf16x8*)&Bs[wn + j * 16 + l16][ca];

            #pragma unroll
            for (int i = 0; i < 2; i++)
                #pragma unroll
                for (int j = 0; j < 4; j++)
                    acc[i][j] = __builtin_amdgcn_mfma_f32_16x16x32_bf16(
                        af[i], bfr[j], acc[i][j], 0, 0, 0);
        }
    }

    // Epilogue: C/D layout col=lane&15 (+nd*16), row=quad*4+reg
    if (ROPE && bn < V_COL) {
        // q/k tile: apply rotate-half RoPE in-lane before bf16 store
        #pragma unroll
        for (int i = 0; i < 2; i++)
            #pragma unroll
            for (int r = 0; r < 4; r++) {
                const int srow = bm + wm + i * 16 + quad * 4 + r;
                float cv[4], sv[4], o[4];
                #pragma unroll
                for (int nd = 0; nd < 4; nd++) {
                    const int d = nd * 16 + l16;          // head-local dim
                    cv[nd] = cs[srow * HD + d];
                    sv[nd] = sn[srow * HD + d];
                }
                o[0] = acc[i][0][r] * cv[0] - acc[i][2][r] * sv[0];
                o[1] = acc[i][1][r] * cv[1] - acc[i][3][r] * sv[1];
                o[2] = acc[i][2][r] * cv[2] + acc[i][0][r] * sv[2];
                o[3] = acc[i][3][r] * cv[3] + acc[i][1][r] * sv[3];
                #pragma unroll
                for (int nd = 0; nd < 4; nd++) {
                    const int col = bn + wn + nd * 16 + l16;
                    ((ushort_t*)Cp)[(size_t)srow * N + col] = f2bf(o[nd]);
                }
            }
    } else {
        #pragma unroll
        for (int i = 0; i < 2; i++)
            #pragma unroll
            for (int j = 0; j < 4; j++)
                #pragma unroll
                for (int r = 0; r < 4; r++) {
                    int row = bm + wm + i * 16 + quad * 4 + r;
                    int col = bn + wn + j * 16 + l16;
                    if (CF32)
                        ((float*)Cp)[(size_t)row * N + col] = acc[i][j][r];
                    else
                        ((ushort_t*)Cp)[(size_t)row * N + col] = f2bf(acc[i][j][r]);
                }
    }
}

// ---------------------------------------------------------------------------
// Fallback GEMM with fused fp32->bf16 staging (small-ws path; unchanged)
// ---------------------------------------------------------------------------
template<bool AF32, bool BF32, bool CF32>
__global__ __launch_bounds__(256) void gemm_bt(
    const void* __restrict__ Ap, const void* __restrict__ Bp,
    void* __restrict__ Cp, int M, int N, int K) {
    __shared__ ushort_t As[128][40];
    __shared__ ushort_t Bs[128][40];

    const int t    = threadIdx.x;
    const int wave = t >> 6;
    const int lane = t & 63;
    const int quad = lane >> 4;
    const int l16  = lane & 15;
    const int wm   = (wave >> 1) << 6;
    const int wn   = (wave & 1)  << 6;
    const int bm   = blockIdx.y * 128;
    const int bn   = blockIdx.x * 128;
    const int sr   = t >> 2;
    const int sc   = (t & 3) << 3;

    f32x4 acc[4][4];
    #pragma unroll
    for (int i = 0; i < 4; i++)
        #pragma unroll
        for (int j = 0; j < 4; j++) {
            f32x4 z = {0.f, 0.f, 0.f, 0.f};
            acc[i][j] = z;
        }

    for (int k0 = 0; k0 < K; k0 += 32) {
        __syncthreads();
        if (AF32) {
            const float* A = (const float*)Ap;
            const float* p0 = &A[(size_t)(bm + sr) * K + k0 + sc];
            const float* p1 = &A[(size_t)(bm + sr + 64) * K + k0 + sc];
            float4 a0 = *(const float4*)p0, a1 = *(const float4*)(p0 + 4);
            float4 b0 = *(const float4*)p1, b1 = *(const float4*)(p1 + 4);
            *(uint4*)&As[sr][sc] = make_uint4(
                pk_bf16(a0.x, a0.y), pk_bf16(a0.z, a0.w),
                pk_bf16(a1.x, a1.y), pk_bf16(a1.z, a1.w));
            *(uint4*)&As[sr + 64][sc] = make_uint4(
                pk_bf16(b0.x, b0.y), pk_bf16(b0.z, b0.w),
                pk_bf16(b1.x, b1.y), pk_bf16(b1.z, b1.w));
        } else {
            const ushort_t* A = (const ushort_t*)Ap;
            *(uint4*)&As[sr][sc]      = *(const uint4*)&A[(size_t)(bm + sr) * K + k0 + sc];
            *(uint4*)&As[sr + 64][sc] = *(const uint4*)&A[(size_t)(bm + sr + 64) * K + k0 + sc];
        }
        if (BF32) {
            const float* B = (const float*)Bp;
            const float* p0 = &B[(size_t)(bn + sr) * K + k0 + sc];
            const float* p1 = &B[(size_t)(bn + sr + 64) * K + k0 + sc];
            float4 a0 = *(const float4*)p0, a1 = *(const float4*)(p0 + 4);
            float4 b0 = *(const float4*)p1, b1 = *(const float4*)(p1 + 4);
            *(uint4*)&Bs[sr][sc] = make_uint4(
                pk_bf16(a0.x, a0.y), pk_bf16(a0.z, a0.w),
                pk_bf16(a1.x, a1.y), pk_bf16(a1.z, a1.w));
            *(uint4*)&Bs[sr + 64][sc] = make_uint4(
                pk_bf16(b0.x, b0.y), pk_bf16(b0.z, b0.w),
                pk_bf16(b1.x, b1.y), pk_bf16(b1.z, b1.w));
        } else {
            const ushort_t* B = (const ushort_t*)Bp;
            *(uint4*)&Bs[sr][sc]      = *(const uint4*)&B[(size_t)(bn + sr) * K + k0 + sc];
            *(uint4*)&Bs[sr + 64][sc] = *(const uint4*)&B[(size_t)(bn + sr + 64) * K + k0 + sc];
        }
        __syncthreads();

        bf16x8 af[4], bfr[4];
        #pragma unroll
        for (int i = 0; i < 4; i++)
            af[i] = *(const bf16x8*)&As[wm + i * 16 + l16][quad * 8];
        #pragma unroll
        for (int j = 0; j < 4; j++)
            bfr[j] = *(const bf16x8*)&Bs[wn + j * 16 + l16][quad * 8];

        #pragma unroll
        for (int i = 0; i < 4; i++)
            #pragma unroll
            for (int j = 0; j < 4; j++)
                acc[i][j] = __builtin_amdgcn_mfma_f32_16x16x32_bf16(
                    af[i], bfr[j], acc[i][j], 0, 0, 0);
    }

    #pragma unroll
    for (int i = 0; i < 4; i++)
        #pragma unroll
        for (int j = 0; j < 4; j++)
            #pragma unroll
            for (int r = 0; r < 4; r++) {
                int row = bm + wm + i * 16 + quad * 4 + r;
                int col = bn + wn + j * 16 + l16;
                if (CF32)
                    ((float*)Cp)[(size_t)row * N + col] = acc[i][j][r];
                else
                    ((ushort_t*)Cp)[(size_t)row * N + col] = f2bf(acc[i][j][r]);
            }
}

// ---------------------------------------------------------------------------
// RoPE standalone (fallback path only — main path fuses into GEMM1 epilogue)
// ---------------------------------------------------------------------------
__global__ __launch_bounds__(256) void rope_kernel(
    ushort_t* __restrict__ qkv, const float* __restrict__ cs,
    const float* __restrict__ sn) {
    int idx = blockIdx.x * 256 + threadIdx.x;
    if (idx >= S_LEN * (NQH + NKVH)) return;
    int s  = idx / (NQH + NKVH);
    int hh = idx - s * (NQH + NKVH);

    ushort_t* p = &qkv[(size_t)s * QKV_O + hh * HD];
    const uint4* p4 = (const uint4*)p;
    float v[HD], c[HD], sv[HD];
    #pragma unroll
    for (int b = 0; b < 8; b++) unpack8(&v[b * 8], p4[b]);
    const float4* c4 = (const float4*)&cs[s * HD];
    const float4* s4 = (const float4*)&sn[s * HD];
    #pragma unroll
    for (int b = 0; b < 16; b++) {
        ((float4*)c)[b]  = c4[b];
        ((float4*)sv)[b] = s4[b];
    }
    float o[HD];
    #pragma unroll
    for (int d = 0; d < 32; d++) {
        o[d]      = v[d] * c[d]           - v[d + 32] * sv[d];
        o[d + 32] = v[d + 32] * c[d + 32] + v[d]      * sv[d + 32];
    }
    unsigned int* pw = (unsigned int*)p;
    #pragma unroll
    for (int d = 0; d < HD; d += 2)
        pw[d >> 1] = pk_bf16(o[d], o[d + 1]);
}

// ---------------------------------------------------------------------------
// attn_v5: complementary pairing + S^T orientation + dbuf K/V staging
// (unchanged from round 12 — 48.5 us)
// ---------------------------------------------------------------------------
__global__ __launch_bounds__(256) void attn_v5(
    const ushort_t* __restrict__ qkv, ushort_t* __restrict__ O) {
    const int bx   = blockIdx.x;            // 512 blocks
    const int h    = bx & 31;               // head
    const int p    = bx >> 5;               // pair index 0..15 (p=0 heaviest)
    const int kvh  = h >> 2;                // GQA group size 4
    const int q0d  = (31 - p) * 64;         // deep Q-tile base row
    const int q0s  = p * 64;                // shallow Q-tile base row
    const int tid  = threadIdx.x;
    const int wave = tid >> 6;
    const int lane = tid & 63;
    const int quad = lane >> 4;
    const int l16  = lane & 15;

    __shared__ __align__(16) ushort_t Ks[2][64][72];   // 18.4 KB (dbuf)
    __shared__ __align__(16) ushort_t Vt[2][64][72];   // 18.4 KB (dbuf)
    __shared__ __align__(16) ushort_t Pl[4][32][72];   // 18.4 KB

    const int rowbase0 = q0d + wave * 16;   // mi=0 (deep)
    const int rowbase1 = q0s + wave * 16;   // mi=1 (shallow)

    bf16x8 bq[2][2];
    #pragma unroll
    for (int mi = 0; mi < 2; mi++) {
        const int rb = (mi == 0) ? rowbase0 : rowbase1;
        #pragma unroll
        for (int ks = 0; ks < 2; ks++) {
            uint4 u = *(const uint4*)&qkv[(size_t)(rb + l16) * QKV_O
                                          + h * HD + ks * 32 + quad * 8];
            float f[8]; unpack8(f, u);
            uint4 w = make_uint4(
                pk_bf16(f[0] * 0.125f, f[1] * 0.125f),
                pk_bf16(f[2] * 0.125f, f[3] * 0.125f),
                pk_bf16(f[4] * 0.125f, f[5] * 0.125f),
                pk_bf16(f[6] * 0.125f, f[7] * 0.125f));
            __builtin_memcpy(&bq[mi][ks], &w, 16);
        }
    }

    bf16x8 ones;
    #pragma unroll
    for (int e = 0; e < 8; e++) ones[e] = (__bf16)1.0f;

    f32x4 acc_o[2][4];
    f32x4 acc_l[2];
    #pragma unroll
    for (int mi = 0; mi < 2; mi++) {
        f32x4 z = {0.f, 0.f, 0.f, 0.f};
        acc_l[mi] = z;
        #pragma unroll
        for (int n = 0; n < 4; n++) acc_o[mi][n] = z;
    }

    const int nt = 32 - p;               // K tiles for the deep tile
    const int sr = tid >> 2;             // staging kcol 0..63
    const int sc = (tid & 3) << 4;       // staging d {0,16,32,48}

    // ---- prologue: stage tile 0 into buffer 0 ----
    {
        const ushort_t* kp = &qkv[(size_t)sr * QKV_O + K_COL + kvh * HD + sc];
        *(uint4*)&Ks[0][sr][sc]     = *(const uint4*)kp;
        *(uint4*)&Ks[0][sr][sc + 8] = *(const uint4*)(kp + 8);
        const ushort_t* vp = &qkv[(size_t)sr * QKV_O + V_COL + kvh * HD + sc];
        ushort_t tmp[16];
        *(uint4*)&tmp[0] = *(const uint4*)vp;
        *(uint4*)&tmp[8] = *(const uint4*)(vp + 8);
        #pragma unroll
        for (int e = 0; e < 16; e++) {
            int d = sc + e;
            Vt[0][d][(sr + 8 * (d >> 3)) & 63] = tmp[e];
        }
    }
    __syncthreads();

    for (int t = 0; t < nt; t++) {
        const int cur = t & 1, nxt = cur ^ 1;
        const int j0 = t * 64;
        const bool hasNext = (t + 1 < nt);   // block-uniform

        uint4 ka, kb, va, vb;
        if (hasNext) {
            const size_t rbase = (size_t)(j0 + 64 + sr) * QKV_O;
            const ushort_t* kp = &qkv[rbase + K_COL + kvh * HD + sc];
            ka = *(const uint4*)kp; kb = *(const uint4*)(kp + 8);
            const ushort_t* vp = &qkv[rbase + V_COL + kvh * HD + sc];
            va = *(const uint4*)vp; vb = *(const uint4*)(vp + 8);
        }

        const bool sact = (t <= p);          // shallow active (block-uniform)

        f32x4 st[2][4];
        #pragma unroll
        for (int mi = 0; mi < 2; mi++)
            #pragma unroll
            for (int nk = 0; nk < 4; nk++) {
                f32x4 z = {0.f, 0.f, 0.f, 0.f};
                st[mi][nk] = z;
            }
        #pragma unroll
        for (int ks = 0; ks < 2; ks++) {
            bf16x8 ak[4];
            #pragma unroll
            for (int nk = 0; nk < 4; nk++)
                ak[nk] = *(const bf16x8*)&Ks[cur][nk * 16 + l16][ks * 32 + quad * 8];
            #pragma unroll
            for (int mi = 0; mi < 2; mi++) {
                if (mi == 1 && !sact) continue;       // uniform, post-unroll
                #pragma unroll
                for (int nk = 0; nk < 4; nk++)
                    st[mi][nk] = __builtin_amdgcn_mfma_f32_16x16x32_bf16(
                        ak[nk], bq[mi][ks], st[mi][nk], 0, 0, 0);
            }
        }

        #pragma unroll
        for (int mi = 0; mi < 2; mi++) {
            if (mi == 1 && !sact) continue;           // uniform, post-unroll
            const bool diag = (mi == 0) ? (t == nt - 1) : (t == p);
            const int qrow = ((mi == 0) ? rowbase0 : rowbase1) + l16;
            #pragma unroll
            for (int nk = 0; nk < 4; nk++) {
                const int kc0 = j0 + nk * 16 + quad * 4;
                float pv[4];
                #pragma unroll
                for (int r = 0; r < 4; r++) {
                    float e = __expf(st[mi][nk][r]);
                    pv[r] = (diag && (kc0 + r > qrow)) ? 0.f : e;
                }
                uint2 w2 = make_uint2(pk_bf16(pv[0], pv[1]), pk_bf16(pv[2], pv[3]));
                *(uint2*)&Pl[wave][mi * 16 + l16][nk * 16 + quad * 4] = w2;
            }
        }

        #pragma unroll
        for (int ksp = 0; ksp < 2; ksp++) {
            bf16x8 bv[4];
            #pragma unroll
            for (int nd = 0; nd < 4; nd++) {
                const int d = nd * 16 + l16;
                bv[nd] = *(const bf16x8*)&Vt[cur][d][(ksp * 32 + quad * 8 + 8 * (d >> 3)) & 63];
            }
            #pragma unroll
            for (int mi = 0; mi < 2; mi++) {
                if (mi == 1 && !sact) continue;       // uniform, post-unroll
                bf16x8 ap = *(const bf16x8*)&Pl[wave][mi * 16 + l16][ksp * 32 + quad * 8];
                acc_l[mi] = __builtin_amdgcn_mfma_f32_16x16x32_bf16(
                    ap, ones, acc_l[mi], 0, 0, 0);
                #pragma unroll
                for (int nd = 0; nd < 4; nd++)
                    acc_o[mi][nd] = __builtin_amdgcn_mfma_f32_16x16x32_bf16(
                        ap, bv[nd], acc_o[mi][nd], 0, 0, 0);
            }
        }

        if (hasNext) {
            *(uint4*)&Ks[nxt][sr][sc]     = ka;
            *(uint4*)&Ks[nxt][sr][sc + 8] = kb;
            ushort_t tmp[16];
            *(uint4*)&tmp[0] = va;
            *(uint4*)&tmp[8] = vb;
            #pragma unroll
            for (int e = 0; e < 16; e++) {
                int d = sc + e;
                Vt[nxt][d][(sr + 8 * (d >> 3)) & 63] = tmp[e];
            }
        }
        __syncthreads();   // ONE barrier per tile
    }

    #pragma unroll
    for (int mi = 0; mi < 2; mi++) {
        const int rb = (mi == 0) ? rowbase0 : rowbase1;
        float inv[4];
        #pragma unroll
        for (int r = 0; r < 4; r++) inv[r] = 1.0f / acc_l[mi][r];
        #pragma unroll
        for (int nd = 0; nd < 4; nd++)
            #pragma unroll
            for (int r = 0; r < 4; r++) {
                int row = rb + quad * 4 + r;
                int col = h * HD + nd * 16 + l16;
                O[(size_t)row * (NQH * HD) + col] = f2bf(acc_o[mi][nd][r] * inv[r]);
            }
    }
}

// ---------------------------------------------------------------------------
extern "C" void kernel_launch(void* const* d_in, const int* in_sizes, int n_in,
                              void* d_out, int out_size, void* d_ws, size_t ws_size,
                              hipStream_t stream) {
    const float* x     = (const float*)d_in[0];  // [2048][2048] fp32
    const float* cosp  = (const float*)d_in[1];  // [2048][64]   fp32
    const float* sinp  = (const float*)d_in[2];  // [2048][64]   fp32
    const float* w_qkv = (const float*)d_in[3];  // [3072][2048] fp32
    const float* w_out = (const float*)d_in[4];  // [2048][2048] fp32
    float* out = (float*)d_out;                  // [2048][2048] fp32

    const size_t NQKV = (size_t)S_LEN * QKV_O;   // 6291456
    const size_t NH2  = (size_t)S_LEN * HID;     // 4194304
    const size_t need = 2 * (NQKV + NH2) * sizeof(ushort_t);  // 41.9 MB

    ushort_t* qkv = (ushort_t*)d_ws;             // bf16 [2048][3072]

    if (ws_size >= need) {
        ushort_t* x_bf    = qkv + NQKV;
        ushort_t* attnO   = x_bf;                // disjoint lifetimes
        ushort_t* wqkv_bf = x_bf + NH2;
        ushort_t* wout_bf = wqkv_bf + NQKV;

        convert3<<<XN8 / 256 + QN8 / 256 + ON8 / 256, 256, 0, stream>>>(
            x, w_qkv, w_out, x_bf, wqkv_bf, wout_bf);

        // 1) qkv = x @ w_qkv^T with FUSED RoPE epilogue (rope pass eliminated)
        dim3 g1(QKV_O / 128, S_LEN / 64);
        gemm_bk64<false, true><<<g1, 256, 0, stream>>>(
            x_bf, wqkv_bf, qkv, S_LEN, QKV_O, HID, cosp, sinp);

        // 2) causal GQA attention
        attn_v5<<<16 * NQH, 256, 0, stream>>>(qkv, attnO);

        // 3) out = attnO @ w_out^T
        dim3 g2(HID / 128, S_LEN / 64);
        gemm_bk64<true, false><<<g2, 256, 0, stream>>>(
            attnO, wout_bf, out, S_LEN, HID, HID, nullptr, nullptr);
    } else {
        ushort_t* attnO = qkv + NQKV;

        dim3 g1(QKV_O / 128, S_LEN / 128);
        gemm_bt<true, true, false><<<g1, 256, 0, stream>>>(x, w_qkv, qkv, S_LEN, QKV_O, HID);

        int rope_threads = S_LEN * (NQH + NKVH);
        rope_kernel<<<(rope_threads + 255) / 256, 256, 0, stream>>>(qkv, cosp, sinp);

        attn_v5<<<16 * NQH, 256, 0, stream>>>(qkv, attnO);

        dim3 g2(HID / 128, S_LEN / 128);
        gemm_bt<false, true, true><<<g2, 256, 0, stream>>>(attnO, w_out, out, S_LEN, HID, HID);
    }
}

// Round 14
// 208.367 us; speedup vs baseline: 2.3827x; 1.0084x over previous
//
#include <hip/hip_runtime.h>
#include <hip/hip_bf16.h>
#include <stdint.h>

// Problem constants (B=1). I/O dtype: fp32. Internals bf16 (MFMA path).
#define S_LEN 2048
#define HID   2048
#define NQH   32
#define NKVH  8
#define HD    64
#define QKV_O 3072      // (32 + 2*8) * 64
#define K_COL 2048      // col offset of K block in qkv row
#define V_COL 2560      // col offset of V block in qkv row

typedef unsigned short ushort_t;
typedef __bf16 bf16x8 __attribute__((ext_vector_type(8)));
typedef float  f32x4  __attribute__((ext_vector_type(4)));

#define GLB(p) ((const __attribute__((address_space(1))) void*)(p))
#define LDSP(p) ((__attribute__((address_space(3))) void*)(p))

__device__ __forceinline__ ushort_t f2bf(float f) {
    unsigned int x = __float_as_uint(f);
    unsigned int r = (x + 0x7fffu + ((x >> 16) & 1u)) >> 16;   // RNE
    return (ushort_t)r;
}
__device__ __forceinline__ unsigned int pk_bf16(float a, float b) {
    __hip_bfloat162 h = __float22bfloat162_rn(make_float2(a, b));
    unsigned int r;
    __builtin_memcpy(&r, &h, 4);
    return r;
}
__device__ __forceinline__ void unpack8(float* dst, uint4 u) {
    dst[0] = __uint_as_float(u.x << 16); dst[1] = __uint_as_float(u.x & 0xffff0000u);
    dst[2] = __uint_as_float(u.y << 16); dst[3] = __uint_as_float(u.y & 0xffff0000u);
    dst[4] = __uint_as_float(u.z << 16); dst[5] = __uint_as_float(u.z & 0xffff0000u);
    dst[6] = __uint_as_float(u.w << 16); dst[7] = __uint_as_float(u.w & 0xffff0000u);
}

// ---------------------------------------------------------------------------
// convert3: fp32 -> bf16 for x, w_qkv, w_out (unchanged)
// ---------------------------------------------------------------------------
#define XN8 (S_LEN * HID / 8)          // 524288
#define QN8 (QKV_O * HID / 8)          // 786432
#define ON8 (HID * HID / 8)            // 524288

__global__ __launch_bounds__(256) void convert3(
    const float* __restrict__ x, const float* __restrict__ wq,
    const float* __restrict__ wo, ushort_t* __restrict__ xb,
    ushort_t* __restrict__ wqb, ushort_t* __restrict__ wob) {
    int i = blockIdx.x * 256 + threadIdx.x;
    const float* s; ushort_t* d; int off;
    if (i < XN8)            { s = x;  d = xb;  off = i; }
    else if (i < XN8 + QN8) { s = wq; d = wqb; off = i - XN8; }
    else                    { s = wo; d = wob; off = i - XN8 - QN8; }
    const float4* sp = (const float4*)s + (size_t)off * 2;
    float4 a = sp[0], b = sp[1];
    *(uint4*)(d + (size_t)off * 8) = make_uint4(
        pk_bf16(a.x, a.y), pk_bf16(a.z, a.w),
        pk_bf16(b.x, b.y), pk_bf16(b.z, b.w));
}

// ---------------------------------------------------------------------------
// gemm_bk64: pure-bf16 GEMM, 64x128 tile, BK=64, XOR-swizzled LDS.
// ROPE: fused in-lane RoPE epilogue for q/k tiles (bn < V_COL).
// VT:   V tiles (bn >= V_COL) are stored TRANSPOSED to VtG[vcol][seq] —
//       each lane's 4 C-frag regs are 4 consecutive seq rows at one head-dim,
//       so V^T emits as packed b64 stores; attention then needs NO LDS
//       transpose (the round-13 attn VALU hotspot).
// ---------------------------------------------------------------------------
template<bool CF32, bool ROPE, bool VT>
__global__ __launch_bounds__(256) void gemm_bk64(
    const ushort_t* __restrict__ A, const ushort_t* __restrict__ Bt,
    void* __restrict__ Cp, int M, int N, int K,
    const float* __restrict__ cs, const float* __restrict__ sn,
    ushort_t* __restrict__ VtG) {
    __shared__ ushort_t As[64][64];     // 8 KB
    __shared__ ushort_t Bs[128][64];    // 16 KB

    const int t    = threadIdx.x;
    const int wave = t >> 6;
    const int lane = t & 63;
    const int quad = lane >> 4;
    const int l16  = lane & 15;
    const int wm   = (wave >> 1) << 5;
    const int wn   = (wave & 1)  << 6;
    const int bm   = blockIdx.y * 64;
    const int bn   = blockIdx.x * 128;
    const int lr   = lane >> 3;
    const int lc   = ((lane & 7) ^ lr) << 3;

    f32x4 acc[2][4];
    #pragma unroll
    for (int i = 0; i < 2; i++)
        #pragma unroll
        for (int j = 0; j < 4; j++) {
            f32x4 z = {0.f, 0.f, 0.f, 0.f};
            acc[i][j] = z;
        }

    const ushort_t* a0 = &A[(size_t)(bm + wave * 16 + lr) * K + lc];
    const ushort_t* b0 = &Bt[(size_t)(bn + wave * 32 + lr) * K + lc];
    const size_t r8 = (size_t)8 * K;

    for (int k0 = 0; k0 < K; k0 += 64) {
        __syncthreads();
        __builtin_amdgcn_global_load_lds(GLB(a0 + k0),          LDSP(&As[wave * 16][0]),      16, 0, 0);
        __builtin_amdgcn_global_load_lds(GLB(a0 + k0 + r8),     LDSP(&As[wave * 16 + 8][0]),  16, 0, 0);
        __builtin_amdgcn_global_load_lds(GLB(b0 + k0),          LDSP(&Bs[wave * 32][0]),      16, 0, 0);
        __builtin_amdgcn_global_load_lds(GLB(b0 + k0 + r8),     LDSP(&Bs[wave * 32 + 8][0]),  16, 0, 0);
        __builtin_amdgcn_global_load_lds(GLB(b0 + k0 + 2 * r8), LDSP(&Bs[wave * 32 + 16][0]), 16, 0, 0);
        __builtin_amdgcn_global_load_lds(GLB(b0 + k0 + 3 * r8), LDSP(&Bs[wave * 32 + 24][0]), 16, 0, 0);
        __syncthreads();

        #pragma unroll
        for (int ks = 0; ks < 2; ks++) {
            const int ca = (((ks << 2) + quad) ^ (l16 & 7)) << 3;
            bf16x8 af[2], bfr[4];
            #pragma unroll
            for (int i = 0; i < 2; i++)
                af[i] = *(const bf16x8*)&As[wm + i * 16 + l16][ca];
            #pragma unroll
            for (int j = 0; j < 4; j++)
                bfr[j] = *(const bf16x8*)&Bs[wn + j * 16 + l16][ca];

            #pragma unroll
            for (int i = 0; i < 2; i++)
                #pragma unroll
                for (int j = 0; j < 4; j++)
                    acc[i][j] = __builtin_amdgcn_mfma_f32_16x16x32_bf16(
                        af[i], bfr[j], acc[i][j], 0, 0, 0);
        }
    }

    // Epilogue: C/D layout col=lane&15 (+nd*16), row=quad*4+reg
    if (ROPE && bn < V_COL) {
        // q/k tile: rotate-half RoPE in-lane (partner d+-32 = reg nd+-2)
        #pragma unroll
        for (int i = 0; i < 2; i++)
            #pragma unroll
            for (int r = 0; r < 4; r++) {
                const int srow = bm + wm + i * 16 + quad * 4 + r;
                float cv[4], sv[4], o[4];
                #pragma unroll
                for (int nd = 0; nd < 4; nd++) {
                    const int d = nd * 16 + l16;
                    cv[nd] = cs[srow * HD + d];
                    sv[nd] = sn[srow * HD + d];
                }
                o[0] = acc[i][0][r] * cv[0] - acc[i][2][r] * sv[0];
                o[1] = acc[i][1][r] * cv[1] - acc[i][3][r] * sv[1];
                o[2] = acc[i][2][r] * cv[2] + acc[i][0][r] * sv[2];
                o[3] = acc[i][3][r] * cv[3] + acc[i][1][r] * sv[3];
                #pragma unroll
                for (int nd = 0; nd < 4; nd++) {
                    const int col = bn + wn + nd * 16 + l16;
                    ((ushort_t*)Cp)[(size_t)srow * N + col] = f2bf(o[nd]);
                }
            }
    } else if (VT && bn >= V_COL) {
        // V tile: write transposed to VtG[vcol][seq] (b64 packed rows)
        #pragma unroll
        for (int i = 0; i < 2; i++) {
            const int srow0 = bm + wm + i * 16 + quad * 4;
            #pragma unroll
            for (int nd = 0; nd < 4; nd++) {
                const int vcol = bn + wn + nd * 16 + l16 - V_COL;
                uint2 w2 = make_uint2(
                    pk_bf16(acc[i][nd][0], acc[i][nd][1]),
                    pk_bf16(acc[i][nd][2], acc[i][nd][3]));
                *(uint2*)&VtG[(size_t)vcol * S_LEN + srow0] = w2;
            }
        }
    } else {
        #pragma unroll
        for (int i = 0; i < 2; i++)
            #pragma unroll
            for (int j = 0; j < 4; j++)
                #pragma unroll
                for (int r = 0; r < 4; r++) {
                    int row = bm + wm + i * 16 + quad * 4 + r;
                    int col = bn + wn + j * 16 + l16;
                    if (CF32)
                        ((float*)Cp)[(size_t)row * N + col] = acc[i][j][r];
                    else
                        ((ushort_t*)Cp)[(size_t)row * N + col] = f2bf(acc[i][j][r]);
                }
    }
}

// ---------------------------------------------------------------------------
// Fallback GEMM with fused fp32->bf16 staging (small-ws path; unchanged)
// ---------------------------------------------------------------------------
template<bool AF32, bool BF32, bool CF32>
__global__ __launch_bounds__(256) void gemm_bt(
    const void* __restrict__ Ap, const void* __restrict__ Bp,
    void* __restrict__ Cp, int M, int N, int K) {
    __shared__ ushort_t As[128][40];
    __shared__ ushort_t Bs[128][40];

    const int t    = threadIdx.x;
    const int wave = t >> 6;
    const int lane = t & 63;
    const int quad = lane >> 4;
    const int l16  = lane & 15;
    const int wm   = (wave >> 1) << 6;
    const int wn   = (wave & 1)  << 6;
    const int bm   = blockIdx.y * 128;
    const int bn   = blockIdx.x * 128;
    const int sr   = t >> 2;
    const int sc   = (t & 3) << 3;

    f32x4 acc[4][4];
    #pragma unroll
    for (int i = 0; i < 4; i++)
        #pragma unroll
        for (int j = 0; j < 4; j++) {
            f32x4 z = {0.f, 0.f, 0.f, 0.f};
            acc[i][j] = z;
        }

    for (int k0 = 0; k0 < K; k0 += 32) {
        __syncthreads();
        if (AF32) {
            const float* A = (const float*)Ap;
            const float* p0 = &A[(size_t)(bm + sr) * K + k0 + sc];
            const float* p1 = &A[(size_t)(bm + sr + 64) * K + k0 + sc];
            float4 a0 = *(const float4*)p0, a1 = *(const float4*)(p0 + 4);
            float4 b0 = *(const float4*)p1, b1 = *(const float4*)(p1 + 4);
            *(uint4*)&As[sr][sc] = make_uint4(
                pk_bf16(a0.x, a0.y), pk_bf16(a0.z, a0.w),
                pk_bf16(a1.x, a1.y), pk_bf16(a1.z, a1.w));
            *(uint4*)&As[sr + 64][sc] = make_uint4(
                pk_bf16(b0.x, b0.y), pk_bf16(b0.z, b0.w),
                pk_bf16(b1.x, b1.y), pk_bf16(b1.z, b1.w));
        } else {
            const ushort_t* A = (const ushort_t*)Ap;
            *(uint4*)&As[sr][sc]      = *(const uint4*)&A[(size_t)(bm + sr) * K + k0 + sc];
            *(uint4*)&As[sr + 64][sc] = *(const uint4*)&A[(size_t)(bm + sr + 64) * K + k0 + sc];
        }
        if (BF32) {
            const float* B = (const float*)Bp;
            const float* p0 = &B[(size_t)(bn + sr) * K + k0 + sc];
            const float* p1 = &B[(size_t)(bn + sr + 64) * K + k0 + sc];
            float4 a0 = *(const float4*)p0, a1 = *(const float4*)(p0 + 4);
            float4 b0 = *(const float4*)p1, b1 = *(const float4*)(p1 + 4);
            *(uint4*)&Bs[sr][sc] = make_uint4(
                pk_bf16(a0.x, a0.y), pk_bf16(a0.z, a0.w),
                pk_bf16(a1.x, a1.y), pk_bf16(a1.z, a1.w));
            *(uint4*)&Bs[sr + 64][sc] = make_uint4(
                pk_bf16(b0.x, b0.y), pk_bf16(b0.z, b0.w),
                pk_bf16(b1.x, b1.y), pk_bf16(b1.z, b1.w));
        } else {
            const ushort_t* B = (const ushort_t*)Bp;
            *(uint4*)&Bs[sr][sc]      = *(const uint4*)&B[(size_t)(bn + sr) * K + k0 + sc];
            *(uint4*)&Bs[sr + 64][sc] = *(const uint4*)&B[(size_t)(bn + sr + 64) * K + k0 + sc];
        }
        __syncthreads();

        bf16x8 af[4], bfr[4];
        #pragma unroll
        for (int i = 0; i < 4; i++)
            af[i] = *(const bf16x8*)&As[wm + i * 16 + l16][quad * 8];
        #pragma unroll
        for (int j = 0; j < 4; j++)
            bfr[j] = *(const bf16x8*)&Bs[wn + j * 16 + l16][quad * 8];

        #pragma unroll
        for (int i = 0; i < 4; i++)
            #pragma unroll
            for (int j = 0; j < 4; j++)
                acc[i][j] = __builtin_amdgcn_mfma_f32_16x16x32_bf16(
                    af[i], bfr[j], acc[i][j], 0, 0, 0);
    }

    #pragma unroll
    for (int i = 0; i < 4; i++)
        #pragma unroll
        for (int j = 0; j < 4; j++)
            #pragma unroll
            for (int r = 0; r < 4; r++) {
                int row = bm + wm + i * 16 + quad * 4 + r;
                int col = bn + wn + j * 16 + l16;
                if (CF32)
                    ((float*)Cp)[(size_t)row * N + col] = acc[i][j][r];
                else
                    ((ushort_t*)Cp)[(size_t)row * N + col] = f2bf(acc[i][j][r]);
            }
}

// ---------------------------------------------------------------------------
// RoPE standalone (fallback path only)
// ---------------------------------------------------------------------------
__global__ __launch_bounds__(256) void rope_kernel(
    ushort_t* __restrict__ qkv, const float* __restrict__ cs,
    const float* __restrict__ sn) {
    int idx = blockIdx.x * 256 + threadIdx.x;
    if (idx >= S_LEN * (NQH + NKVH)) return;
    int s  = idx / (NQH + NKVH);
    int hh = idx - s * (NQH + NKVH);

    ushort_t* p = &qkv[(size_t)s * QKV_O + hh * HD];
    const uint4* p4 = (const uint4*)p;
    float v[HD], c[HD], sv[HD];
    #pragma unroll
    for (int b = 0; b < 8; b++) unpack8(&v[b * 8], p4[b]);
    const float4* c4 = (const float4*)&cs[s * HD];
    const float4* s4 = (const float4*)&sn[s * HD];
    #pragma unroll
    for (int b = 0; b < 16; b++) {
        ((float4*)c)[b]  = c4[b];
        ((float4*)sv)[b] = s4[b];
    }
    float o[HD];
    #pragma unroll
    for (int d = 0; d < 32; d++) {
        o[d]      = v[d] * c[d]           - v[d + 32] * sv[d];
        o[d + 32] = v[d + 32] * c[d + 32] + v[d]      * sv[d + 32];
    }
    unsigned int* pw = (unsigned int*)p;
    #pragma unroll
    for (int d = 0; d < HD; d += 2)
        pw[d >> 1] = pk_bf16(o[d], o[d + 1]);
}

// ---------------------------------------------------------------------------
// attn_v5: round-12/13 kernel (mid-tier + fallback path; reads V from qkv)
// ---------------------------------------------------------------------------
__global__ __launch_bounds__(256) void attn_v5(
    const ushort_t* __restrict__ qkv, ushort_t* __restrict__ O) {
    const int bx   = blockIdx.x;
    const int h    = bx & 31;
    const int p    = bx >> 5;
    const int kvh  = h >> 2;
    const int q0d  = (31 - p) * 64;
    const int q0s  = p * 64;
    const int tid  = threadIdx.x;
    const int wave = tid >> 6;
    const int lane = tid & 63;
    const int quad = lane >> 4;
    const int l16  = lane & 15;

    __shared__ __align__(16) ushort_t Ks[2][64][72];
    __shared__ __align__(16) ushort_t Vt[2][64][72];
    __shared__ __align__(16) ushort_t Pl[4][32][72];

    const int rowbase0 = q0d + wave * 16;
    const int rowbase1 = q0s + wave * 16;

    bf16x8 bq[2][2];
    #pragma unroll
    for (int mi = 0; mi < 2; mi++) {
        const int rb = (mi == 0) ? rowbase0 : rowbase1;
        #pragma unroll
        for (int ks = 0; ks < 2; ks++) {
            uint4 u = *(const uint4*)&qkv[(size_t)(rb + l16) * QKV_O
                                          + h * HD + ks * 32 + quad * 8];
            float f[8]; unpack8(f, u);
            uint4 w = make_uint4(
                pk_bf16(f[0] * 0.125f, f[1] * 0.125f),
                pk_bf16(f[2] * 0.125f, f[3] * 0.125f),
                pk_bf16(f[4] * 0.125f, f[5] * 0.125f),
                pk_bf16(f[6] * 0.125f, f[7] * 0.125f));
            __builtin_memcpy(&bq[mi][ks], &w, 16);
        }
    }

    bf16x8 ones;
    #pragma unroll
    for (int e = 0; e < 8; e++) ones[e] = (__bf16)1.0f;

    f32x4 acc_o[2][4];
    f32x4 acc_l[2];
    #pragma unroll
    for (int mi = 0; mi < 2; mi++) {
        f32x4 z = {0.f, 0.f, 0.f, 0.f};
        acc_l[mi] = z;
        #pragma unroll
        for (int n = 0; n < 4; n++) acc_o[mi][n] = z;
    }

    const int nt = 32 - p;
    const int sr = tid >> 2;
    const int sc = (tid & 3) << 4;

    {
        const ushort_t* kp = &qkv[(size_t)sr * QKV_O + K_COL + kvh * HD + sc];
        *(uint4*)&Ks[0][sr][sc]     = *(const uint4*)kp;
        *(uint4*)&Ks[0][sr][sc + 8] = *(const uint4*)(kp + 8);
        const ushort_t* vp = &qkv[(size_t)sr * QKV_O + V_COL + kvh * HD + sc];
        ushort_t tmp[16];
        *(uint4*)&tmp[0] = *(const uint4*)vp;
        *(uint4*)&tmp[8] = *(const uint4*)(vp + 8);
        #pragma unroll
        for (int e = 0; e < 16; e++) {
            int d = sc + e;
            Vt[0][d][(sr + 8 * (d >> 3)) & 63] = tmp[e];
        }
    }
    __syncthreads();

    for (int t = 0; t < nt; t++) {
        const int cur = t & 1, nxt = cur ^ 1;
        const int j0 = t * 64;
        const bool hasNext = (t + 1 < nt);

        uint4 ka, kb, va, vb;
        if (hasNext) {
            const size_t rbase = (size_t)(j0 + 64 + sr) * QKV_O;
            const ushort_t* kp = &qkv[rbase + K_COL + kvh * HD + sc];
            ka = *(const uint4*)kp; kb = *(const uint4*)(kp + 8);
            const ushort_t* vp = &qkv[rbase + V_COL + kvh * HD + sc];
            va = *(const uint4*)vp; vb = *(const uint4*)(vp + 8);
        }

        const bool sact = (t <= p);

        f32x4 st[2][4];
        #pragma unroll
        for (int mi = 0; mi < 2; mi++)
            #pragma unroll
            for (int nk = 0; nk < 4; nk++) {
                f32x4 z = {0.f, 0.f, 0.f, 0.f};
                st[mi][nk] = z;
            }
        #pragma unroll
        for (int ks = 0; ks < 2; ks++) {
            bf16x8 ak[4];
            #pragma unroll
            for (int nk = 0; nk < 4; nk++)
                ak[nk] = *(const bf16x8*)&Ks[cur][nk * 16 + l16][ks * 32 + quad * 8];
            #pragma unroll
            for (int mi = 0; mi < 2; mi++) {
                if (mi == 1 && !sact) continue;
                #pragma unroll
                for (int nk = 0; nk < 4; nk++)
                    st[mi][nk] = __builtin_amdgcn_mfma_f32_16x16x32_bf16(
                        ak[nk], bq[mi][ks], st[mi][nk], 0, 0, 0);
            }
        }

        #pragma unroll
        for (int mi = 0; mi < 2; mi++) {
            if (mi == 1 && !sact) continue;
            const bool diag = (mi == 0) ? (t == nt - 1) : (t == p);
            const int qrow = ((mi == 0) ? rowbase0 : rowbase1) + l16;
            #pragma unroll
            for (int nk = 0; nk < 4; nk++) {
                const int kc0 = j0 + nk * 16 + quad * 4;
                float pv[4];
                #pragma unroll
                for (int r = 0; r < 4; r++) {
                    float e = __expf(st[mi][nk][r]);
                    pv[r] = (diag && (kc0 + r > qrow)) ? 0.f : e;
                }
                uint2 w2 = make_uint2(pk_bf16(pv[0], pv[1]), pk_bf16(pv[2], pv[3]));
                *(uint2*)&Pl[wave][mi * 16 + l16][nk * 16 + quad * 4] = w2;
            }
        }

        #pragma unroll
        for (int ksp = 0; ksp < 2; ksp++) {
            bf16x8 bv[4];
            #pragma unroll
            for (int nd = 0; nd < 4; nd++) {
                const int d = nd * 16 + l16;
                bv[nd] = *(const bf16x8*)&Vt[cur][d][(ksp * 32 + quad * 8 + 8 * (d >> 3)) & 63];
            }
            #pragma unroll
            for (int mi = 0; mi < 2; mi++) {
                if (mi == 1 && !sact) continue;
                bf16x8 ap = *(const bf16x8*)&Pl[wave][mi * 16 + l16][ksp * 32 + quad * 8];
                acc_l[mi] = __builtin_amdgcn_mfma_f32_16x16x32_bf16(
                    ap, ones, acc_l[mi], 0, 0, 0);
                #pragma unroll
                for (int nd = 0; nd < 4; nd++)
                    acc_o[mi][nd] = __builtin_amdgcn_mfma_f32_16x16x32_bf16(
                        ap, bv[nd], acc_o[mi][nd], 0, 0, 0);
            }
        }

        if (hasNext) {
            *(uint4*)&Ks[nxt][sr][sc]     = ka;
            *(uint4*)&Ks[nxt][sr][sc + 8] = kb;
            ushort_t tmp[16];
            *(uint4*)&tmp[0] = va;
            *(uint4*)&tmp[8] = vb;
            #pragma unroll
            for (int e = 0; e < 16; e++) {
                int d = sc + e;
                Vt[nxt][d][(sr + 8 * (d >> 3)) & 63] = tmp[e];
            }
        }
        __syncthreads();
    }

    #pragma unroll
    for (int mi = 0; mi < 2; mi++) {
        const int rb = (mi == 0) ? rowbase0 : rowbase1;
        float inv[4];
        #pragma unroll
        for (int r = 0; r < 4; r++) inv[r] = 1.0f / acc_l[mi][r];
        #pragma unroll
        for (int nd = 0; nd < 4; nd++)
            #pragma unroll
            for (int r = 0; r < 4; r++) {
                int row = rb + quad * 4 + r;
                int col = h * HD + nd * 16 + l16;
                O[(size_t)row * (NQH * HD) + col] = f2bf(acc_o[mi][nd][r] * inv[r]);
            }
    }
}

// ---------------------------------------------------------------------------
// attn_v6: complementary pairing + S^T orientation + FULL DMA STAGING.
// K from qkv (row-major) and V^T from VtG (row-major, produced by GEMM1's
// epilogue) both staged via global_load_lds with the round-11 XOR swizzle:
// per-lane source chunk = (lane&7)^(lane>>3); unpadded [64][64] tiles; reads
// use ca = ((g)^(l16&7))*8 — the measured-good gemm_bk64 pattern. Removes
// the 16-scalar V-transpose + VGPR staging round-trip (round-13's VALU
// hotspot: 44% VALUBusy). Dbuf + single barrier per tile kept.
// ---------------------------------------------------------------------------
__global__ __launch_bounds__(256) void attn_v6(
    const ushort_t* __restrict__ qkv, const ushort_t* __restrict__ VtG,
    ushort_t* __restrict__ O) {
    const int bx   = blockIdx.x;            // 512 blocks
    const int h    = bx & 31;
    const int p    = bx >> 5;               // 0..15, p=0 heaviest, first
    const int kvh  = h >> 2;
    const int q0d  = (31 - p) * 64;
    const int q0s  = p * 64;
    const int tid  = threadIdx.x;
    const int wave = tid >> 6;
    const int lane = tid & 63;
    const int quad = lane >> 4;
    const int l16  = lane & 15;

    __shared__ __align__(16) ushort_t Ks[2][64][64];   // 16 KB (DMA, swizzled)
    __shared__ __align__(16) ushort_t Vt[2][64][64];   // 16 KB (DMA, swizzled)
    __shared__ __align__(16) ushort_t Pl[4][32][72];   // 18 KB

    const int rowbase0 = q0d + wave * 16;
    const int rowbase1 = q0s + wave * 16;

    // Q B-frags (lane l16 = qrow), pre-scaled by 1/8
    bf16x8 bq[2][2];
    #pragma unroll
    for (int mi = 0; mi < 2; mi++) {
        const int rb = (mi == 0) ? rowbase0 : rowbase1;
        #pragma unroll
        for (int ks = 0; ks < 2; ks++) {
            uint4 u = *(const uint4*)&qkv[(size_t)(rb + l16) * QKV_O
                                          + h * HD + ks * 32 + quad * 8];
            float f[8]; unpack8(f, u);
            uint4 w = make_uint4(
                pk_bf16(f[0] * 0.125f, f[1] * 0.125f),
                pk_bf16(f[2] * 0.125f, f[3] * 0.125f),
                pk_bf16(f[4] * 0.125f, f[5] * 0.125f),
                pk_bf16(f[6] * 0.125f, f[7] * 0.125f));
            __builtin_memcpy(&bq[mi][ks], &w, 16);
        }
    }

    bf16x8 ones;
    #pragma unroll
    for (int e = 0; e < 8; e++) ones[e] = (__bf16)1.0f;

    f32x4 acc_o[2][4];
    f32x4 acc_l[2];
    #pragma unroll
    for (int mi = 0; mi < 2; mi++) {
        f32x4 z = {0.f, 0.f, 0.f, 0.f};
        acc_l[mi] = z;
        #pragma unroll
        for (int n = 0; n < 4; n++) acc_o[mi][n] = z;
    }

    // DMA lane geometry (XOR swizzle on the source side)
    const int lr = lane >> 3;                 // row-in-group 0..7
    const int cg = ((lane & 7) ^ lr) << 3;    // swizzled global chunk (elems)
    const ushort_t* kbase = &qkv[(size_t)(wave * 16 + lr) * QKV_O + K_COL + kvh * HD + cg];
    const size_t    kr8   = (size_t)8 * QKV_O;
    const ushort_t* vbase = &VtG[(size_t)(kvh * HD + wave * 16 + lr) * S_LEN + cg];
    const size_t    vr8   = (size_t)8 * S_LEN;

    const int nt = 32 - p;

    // ---- prologue: DMA tile 0 -> buffer 0 ----
    __builtin_amdgcn_global_load_lds(GLB(kbase),       LDSP(&Ks[0][wave * 16][0]),     16, 0, 0);
    __builtin_amdgcn_global_load_lds(GLB(kbase + kr8), LDSP(&Ks[0][wave * 16 + 8][0]), 16, 0, 0);
    __builtin_amdgcn_global_load_lds(GLB(vbase),       LDSP(&Vt[0][wave * 16][0]),     16, 0, 0);
    __builtin_amdgcn_global_load_lds(GLB(vbase + vr8), LDSP(&Vt[0][wave * 16 + 8][0]), 16, 0, 0);
    __syncthreads();

    for (int t = 0; t < nt; t++) {
        const int cur = t & 1, nxt = cur ^ 1;
        const int j0 = t * 64;

        // ---- DMA-prefetch tile t+1 -> alternate buffer (flies during compute)
        if (t + 1 < nt) {
            const size_t kj = (size_t)(j0 + 64) * QKV_O;
            __builtin_amdgcn_global_load_lds(GLB(kbase + kj),           LDSP(&Ks[nxt][wave * 16][0]),     16, 0, 0);
            __builtin_amdgcn_global_load_lds(GLB(kbase + kj + kr8),     LDSP(&Ks[nxt][wave * 16 + 8][0]), 16, 0, 0);
            __builtin_amdgcn_global_load_lds(GLB(vbase + j0 + 64),      LDSP(&Vt[nxt][wave * 16][0]),     16, 0, 0);
            __builtin_amdgcn_global_load_lds(GLB(vbase + j0 + 64 + vr8),LDSP(&Vt[nxt][wave * 16 + 8][0]), 16, 0, 0);
        }

        const bool sact = (t <= p);          // shallow active (block-uniform)

        // ---- S^T = K·Q^T ----
        f32x4 st[2][4];
        #pragma unroll
        for (int mi = 0; mi < 2; mi++)
            #pragma unroll
            for (int nk = 0; nk < 4; nk++) {
                f32x4 z = {0.f, 0.f, 0.f, 0.f};
                st[mi][nk] = z;
            }
        #pragma unroll
        for (int ks = 0; ks < 2; ks++) {
            const int ca = (((ks << 2) + quad) ^ (l16 & 7)) << 3;
            bf16x8 ak[4];
            #pragma unroll
            for (int nk = 0; nk < 4; nk++)
                ak[nk] = *(const bf16x8*)&Ks[cur][nk * 16 + l16][ca];
            #pragma unroll
            for (int mi = 0; mi < 2; mi++) {
                if (mi == 1 && !sact) continue;
                #pragma unroll
                for (int nk = 0; nk < 4; nk++)
                    st[mi][nk] = __builtin_amdgcn_mfma_f32_16x16x32_bf16(
                        ak[nk], bq[mi][ks], st[mi][nk], 0, 0, 0);
            }
        }

        // ---- exp + causal mask, b64 P stores ----
        #pragma unroll
        for (int mi = 0; mi < 2; mi++) {
            if (mi == 1 && !sact) continue;
            const bool diag = (mi == 0) ? (t == nt - 1) : (t == p);
            const int qrow = ((mi == 0) ? rowbase0 : rowbase1) + l16;
            #pragma unroll
            for (int nk = 0; nk < 4; nk++) {
                const int kc0 = j0 + nk * 16 + quad * 4;
                float pv[4];
                #pragma unroll
                for (int r = 0; r < 4; r++) {
                    float e = __expf(st[mi][nk][r]);
                    pv[r] = (diag && (kc0 + r > qrow)) ? 0.f : e;
                }
                uint2 w2 = make_uint2(pk_bf16(pv[0], pv[1]), pk_bf16(pv[2], pv[3]));
                *(uint2*)&Pl[wave][mi * 16 + l16][nk * 16 + quad * 4] = w2;
            }
        }

        // ---- l += P·1 ; O += P·V ----
        #pragma unroll
        for (int ksp = 0; ksp < 2; ksp++) {
            const int ca = (((ksp << 2) + quad) ^ (l16 & 7)) << 3;
            bf16x8 bv[4];
            #pragma unroll
            for (int nd = 0; nd < 4; nd++)
                bv[nd] = *(const bf16x8*)&Vt[cur][nd * 16 + l16][ca];
            #pragma unroll
            for (int mi = 0; mi < 2; mi++) {
                if (mi == 1 && !sact) continue;
                bf16x8 ap = *(const bf16x8*)&Pl[wave][mi * 16 + l16][ksp * 32 + quad * 8];
                acc_l[mi] = __builtin_amdgcn_mfma_f32_16x16x32_bf16(
                    ap, ones, acc_l[mi], 0, 0, 0);
                #pragma unroll
                for (int nd = 0; nd < 4; nd++)
                    acc_o[mi][nd] = __builtin_amdgcn_mfma_f32_16x16x32_bf16(
                        ap, bv[nd], acc_o[mi][nd], 0, 0, 0);
            }
        }
        __syncthreads();   // one barrier/tile; compiler drains vmcnt here
    }

    // ---- epilogue: O / l ----
    #pragma unroll
    for (int mi = 0; mi < 2; mi++) {
        const int rb = (mi == 0) ? rowbase0 : rowbase1;
        float inv[4];
        #pragma unroll
        for (int r = 0; r < 4; r++) inv[r] = 1.0f / acc_l[mi][r];
        #pragma unroll
        for (int nd = 0; nd < 4; nd++)
            #pragma unroll
            for (int r = 0; r < 4; r++) {
                int row = rb + quad * 4 + r;
                int col = h * HD + nd * 16 + l16;
                O[(size_t)row * (NQH * HD) + col] = f2bf(acc_o[mi][nd][r] * inv[r]);
            }
    }
}

// ---------------------------------------------------------------------------
extern "C" void kernel_launch(void* const* d_in, const int* in_sizes, int n_in,
                              void* d_out, int out_size, void* d_ws, size_t ws_size,
                              hipStream_t stream) {
    const float* x     = (const float*)d_in[0];  // [2048][2048] fp32
    const float* cosp  = (const float*)d_in[1];  // [2048][64]   fp32
    const float* sinp  = (const float*)d_in[2];  // [2048][64]   fp32
    const float* w_qkv = (const float*)d_in[3];  // [3072][2048] fp32
    const float* w_out = (const float*)d_in[4];  // [2048][2048] fp32
    float* out = (float*)d_out;                  // [2048][2048] fp32

    const size_t NQKV = (size_t)S_LEN * QKV_O;   // 6291456
    const size_t NH2  = (size_t)S_LEN * HID;     // 4194304
    const size_t NVT  = (size_t)(NKVH * HD) * S_LEN;  // 1048576
    const size_t need_old = 2 * (NQKV + NH2) * sizeof(ushort_t);        // 41.9 MB
    const size_t need_new = need_old + NVT * sizeof(ushort_t);          // 44.0 MB

    ushort_t* qkv = (ushort_t*)d_ws;             // bf16 [2048][3072]
    ushort_t* x_bf    = qkv + NQKV;
    ushort_t* attnO   = x_bf;                    // disjoint lifetimes
    ushort_t* wqkv_bf = x_bf + NH2;
    ushort_t* wout_bf = wqkv_bf + NQKV;
    ushort_t* VtG     = wout_bf + NH2;           // bf16 [512][2048]

    if (ws_size >= need_new) {
        convert3<<<XN8 / 256 + QN8 / 256 + ON8 / 256, 256, 0, stream>>>(
            x, w_qkv, w_out, x_bf, wqkv_bf, wout_bf);

        // 1) qkv(q,k w/ RoPE) + VtG(V^T) = x @ w_qkv^T
        dim3 g1(QKV_O / 128, S_LEN / 64);
        gemm_bk64<false, true, true><<<g1, 256, 0, stream>>>(
            x_bf, wqkv_bf, qkv, S_LEN, QKV_O, HID, cosp, sinp, VtG);

        // 2) causal GQA attention (full DMA staging)
        attn_v6<<<16 * NQH, 256, 0, stream>>>(qkv, VtG, attnO);

        // 3) out = attnO @ w_out^T
        dim3 g2(HID / 128, S_LEN / 64);
        gemm_bk64<true, false, false><<<g2, 256, 0, stream>>>(
            attnO, wout_bf, out, S_LEN, HID, HID, nullptr, nullptr, nullptr);
    } else if (ws_size >= need_old) {
        // round-13 path (no VtG room)
        convert3<<<XN8 / 256 + QN8 / 256 + ON8 / 256, 256, 0, stream>>>(
            x, w_qkv, w_out, x_bf, wqkv_bf, wout_bf);

        dim3 g1(QKV_O / 128, S_LEN / 64);
        gemm_bk64<false, true, false><<<g1, 256, 0, stream>>>(
            x_bf, wqkv_bf, qkv, S_LEN, QKV_O, HID, cosp, sinp, nullptr);

        attn_v5<<<16 * NQH, 256, 0, stream>>>(qkv, attnO);

        dim3 g2(HID / 128, S_LEN / 64);
        gemm_bk64<true, false, false><<<g2, 256, 0, stream>>>(
            attnO, wout_bf, out, S_LEN, HID, HID, nullptr, nullptr, nullptr);
    } else {
        ushort_t* attnO2 = qkv + NQKV;

        dim3 g1(QKV_O / 128, S_LEN / 128);
        gemm_bt<true, true, false><<<g1, 256, 0, stream>>>(x, w_qkv, qkv, S_LEN, QKV_O, HID);

        int rope_threads = S_LEN * (NQH + NKVH);
        rope_kernel<<<(rope_threads + 255) / 256, 256, 0, stream>>>(qkv, cosp, sinp);

        attn_v5<<<16 * NQH, 256, 0, stream>>>(qkv, attnO2);

        dim3 g2(HID / 128, S_LEN / 128);
        gemm_bt<false, true, true><<<g2, 256, 0, stream>>>(attnO2, w_out, out, S_LEN, HID, HID);
    }
}